// Round 9
// baseline (626.447 us; speedup 1.0000x reference)
//
#include <hip/hip_runtime.h>
#include <hip/hip_bf16.h>

typedef __bf16 bf16x8 __attribute__((ext_vector_type(8)));
typedef __bf16 bf16x4 __attribute__((ext_vector_type(4)));
typedef float  f32x4  __attribute__((ext_vector_type(4)));

#define GLOAD_LDS16(gp, lp) \
  __builtin_amdgcn_global_load_lds((const __attribute__((address_space(1))) void*)(gp), \
                                   (__attribute__((address_space(3))) void*)(lp), 16, 0, 0)
#define LGKM0 asm volatile("s_waitcnt lgkmcnt(0)" ::: "memory")

// ---------------- utility kernels ----------------

__global__ __launch_bounds__(256) void zero_f32(float* __restrict__ p, int n) {
  int i = (blockIdx.x * 256 + threadIdx.x) * 4;
  if (i < n) *(float4*)(p + i) = make_float4(0.f, 0.f, 0.f, 0.f);
}

__global__ __launch_bounds__(256) void cvt_f32_bf16(const float* __restrict__ in,
                                                    __bf16* __restrict__ out, long n) {
  long i = ((long)blockIdx.x * 256 + threadIdx.x) * 4;
  if (i >= n) return;
  float4 v = *(const float4*)(in + i);
  bf16x4 o;
  o[0] = (__bf16)v.x; o[1] = (__bf16)v.y; o[2] = (__bf16)v.z; o[3] = (__bf16)v.w;
  *(bf16x4*)(out + i) = o;
}

// W [K][N] f32 row-major  ->  WT [N][K] bf16 row-major
__global__ __launch_bounds__(256) void cvt_wT(const float* __restrict__ W,
                                              __bf16* __restrict__ WT, int K, int N) {
  __shared__ float t[32][33];
  int k0 = blockIdx.x * 32, n0 = blockIdx.y * 32;
  int tx = threadIdx.x, ty = threadIdx.y;   // block (32,8)
  #pragma unroll
  for (int i = 0; i < 32; i += 8)
    t[ty + i][tx] = W[(size_t)(k0 + ty + i) * N + n0 + tx];
  __syncthreads();
  #pragma unroll
  for (int i = 0; i < 32; i += 8)
    WT[(size_t)(n0 + ty + i) * K + k0 + tx] = (__bf16)t[tx][ty + i];
}

// ---- 256x256 GEMM, BK=64, m201 phase structure:  C = A @ BT^T ----
// 512 threads (8 waves 2Mx4N), dbuf LDS 128 KiB as 2 x {A.k0,A.k1,B.k0,B.k1}.
// Phase = {ds_reads; stage one K-half; BARRIER; lgkm(0); setprio+16 MFMA; BARRIER}
// (reads/stages issue BEFORE the opening barrier -> LDS pipe overlaps barrier wait).
// vmcnt(8) only before closing barriers of p2/p4 (tail peels 8->4->0).
// XCD-aware block swizzle (grids are %8==0): contiguous tiles per XCD, bx-fast.
// Swizzle (bank): linear LDS dest; source octet o^((row>>1)&3); same on read.

enum { EPI_BF16 = 0, EPI_F32_BIAS = 1, EPI_BF16_SILU = 2, EPI_BF16_BIAS = 3 };

template <int EPI>
__global__ __launch_bounds__(512, 1)
void gemm256(const __bf16* __restrict__ A, const __bf16* __restrict__ B,
             void* __restrict__ Cout, const float* __restrict__ bias,
             int M, int N, int K) {
  __shared__ __bf16 lds[65536];   // 128 KiB
  const int tid = threadIdx.x;
  const int w = tid >> 6, l = tid & 63;

  // XCD swizzle: hardware id h -> logical tile (h&7)*chunk + h>>3
  const int gx = gridDim.x;
  const int nwg = gx * gridDim.y;
  int h = blockIdx.y * gx + blockIdx.x;
  int lid = ((nwg & 7) == 0) ? ((h & 7) * (nwg >> 3) + (h >> 3)) : h;
  const int brow = (lid % gx) * 256;
  const int bcol = (lid / gx) * 256;

  const int wr = w >> 2, wc = w & 3;            // wave grid 2x4
  const int lr = l & 15;
  const int rdo8 = ((l >> 4) ^ ((lr >> 1) & 3)) << 3;   // swizzled read octet
  const int NT = K >> 6;                         // BK = 64

  // per-lane read bases within a buffer (elems)
  const int aoff = (wr * 128 + lr) * 32 + rdo8;
  const int boff = 16384 + (wc * 64 + lr) * 32 + rdo8;

  // staging geometry: lane covers row j*128 + w*16 + (l>>2), octet l&3,
  // source octet swizzled by ((l>>3)&3)
  const int srow = w * 16 + (l >> 2);
  const int soct8 = ((l & 3) ^ ((l >> 3) & 3)) * 8;
  const __bf16* pA0 = A + (size_t)(brow + srow) * K + soct8;
  const __bf16* pA1 = A + (size_t)(brow + 128 + srow) * K + soct8;
  const __bf16* pB0 = B + (size_t)(bcol + srow) * K + soct8;
  const __bf16* pB1 = B + (size_t)(bcol + 128 + srow) * K + soct8;

  auto stageA = [&](int k, int Tt) {   // K-half k of tile Tt -> buf (Tt&1)
    size_t cofs = (size_t)Tt * 64 + k * 32;
    __bf16* d = lds + (Tt & 1) * 32768 + k * 8192 + w * 512;   // wave-uniform
    GLOAD_LDS16(pA0 + cofs, d);
    GLOAD_LDS16(pA1 + cofs, d + 4096);
  };
  auto stageB = [&](int k, int Tt) {
    size_t cofs = (size_t)Tt * 64 + k * 32;
    __bf16* d = lds + (Tt & 1) * 32768 + 16384 + k * 8192 + w * 512;
    GLOAD_LDS16(pB0 + cofs, d);
    GLOAD_LDS16(pB1 + cofs, d + 4096);
  };

  f32x4 acc[8][4] = {};
  bf16x8 afr[4], bfr[4];

  // prologue: (0).a0,(0).b0,(0).a1,(0).b1,(1).a0,(1).b0 = 12 loads; first 4 drained
  stageA(0, 0); stageB(0, 0);
  stageA(1, 0); stageB(1, 0);
  stageA(0, 1); stageB(0, 1);
  asm volatile("s_waitcnt vmcnt(8)" ::: "memory");
  __builtin_amdgcn_s_barrier();

  for (int T = 0; T < NT; ++T) {
    const int buf = (T & 1) * 32768;
    const bool s1 = (T + 1 < NT), s2 = (T + 2 < NT);

    // ---- p1: (mh0,kk0); stage A1(T+1) ----
    {
      const __bf16* pb = lds + buf + boff;
      const __bf16* pa = lds + buf + aoff;
      #pragma unroll
      for (int n = 0; n < 4; ++n) bfr[n] = *(const bf16x8*)(pb + n * 512);
      #pragma unroll
      for (int m = 0; m < 4; ++m) afr[m] = *(const bf16x8*)(pa + m * 512);
      if (s1) stageA(1, T + 1);
      __builtin_amdgcn_s_barrier();
      LGKM0;
      __builtin_amdgcn_s_setprio(1);
      #pragma unroll
      for (int m = 0; m < 4; ++m)
        #pragma unroll
        for (int n = 0; n < 4; ++n)
          acc[m][n] = __builtin_amdgcn_mfma_f32_16x16x32_bf16(afr[m], bfr[n], acc[m][n], 0, 0, 0);
      __builtin_amdgcn_s_setprio(0);
      __builtin_amdgcn_s_barrier();
    }

    // ---- p2: (mh1,kk0); stage B1(T+1); vmcnt before close ----
    {
      const __bf16* pa = lds + buf + aoff + 2048;
      #pragma unroll
      for (int m = 0; m < 4; ++m) afr[m] = *(const bf16x8*)(pa + m * 512);
      if (s1) stageB(1, T + 1);
      __builtin_amdgcn_s_barrier();
      LGKM0;
      __builtin_amdgcn_s_setprio(1);
      #pragma unroll
      for (int m = 0; m < 4; ++m)
        #pragma unroll
        for (int n = 0; n < 4; ++n)
          acc[m + 4][n] = __builtin_amdgcn_mfma_f32_16x16x32_bf16(afr[m], bfr[n], acc[m + 4][n], 0, 0, 0);
      __builtin_amdgcn_s_setprio(0);
      if (s1) asm volatile("s_waitcnt vmcnt(8)" ::: "memory");
      else    asm volatile("s_waitcnt vmcnt(0)" ::: "memory");
      __builtin_amdgcn_s_barrier();
    }

    // ---- p3: (mh0,kk1); stage A0(T+2) ----
    {
      const __bf16* pb = lds + buf + 8192 + boff;
      const __bf16* pa = lds + buf + 8192 + aoff;
      #pragma unroll
      for (int n = 0; n < 4; ++n) bfr[n] = *(const bf16x8*)(pb + n * 512);
      #pragma unroll
      for (int m = 0; m < 4; ++m) afr[m] = *(const bf16x8*)(pa + m * 512);
      if (s2) stageA(0, T + 2);
      __builtin_amdgcn_s_barrier();
      LGKM0;
      __builtin_amdgcn_s_setprio(1);
      #pragma unroll
      for (int m = 0; m < 4; ++m)
        #pragma unroll
        for (int n = 0; n < 4; ++n)
          acc[m][n] = __builtin_amdgcn_mfma_f32_16x16x32_bf16(afr[m], bfr[n], acc[m][n], 0, 0, 0);
      __builtin_amdgcn_s_setprio(0);
      __builtin_amdgcn_s_barrier();
    }

    // ---- p4: (mh1,kk1); stage B0(T+2); vmcnt tail ----
    {
      const __bf16* pa = lds + buf + 8192 + aoff + 2048;
      #pragma unroll
      for (int m = 0; m < 4; ++m) afr[m] = *(const bf16x8*)(pa + m * 512);
      if (s2) stageB(0, T + 2);
      __builtin_amdgcn_s_barrier();
      LGKM0;
      __builtin_amdgcn_s_setprio(1);
      #pragma unroll
      for (int m = 0; m < 4; ++m)
        #pragma unroll
        for (int n = 0; n < 4; ++n)
          acc[m + 4][n] = __builtin_amdgcn_mfma_f32_16x16x32_bf16(afr[m], bfr[n], acc[m + 4][n], 0, 0, 0);
      __builtin_amdgcn_s_setprio(0);
      if (s2)      asm volatile("s_waitcnt vmcnt(8)" ::: "memory");
      else if (s1) asm volatile("s_waitcnt vmcnt(4)" ::: "memory");
      __builtin_amdgcn_s_barrier();
    }
  }

  // epilogue (validated mapping)
  #pragma unroll
  for (int m = 0; m < 8; ++m) {
    int row0 = brow + wr * 128 + m * 16 + (l >> 4) * 4;
    #pragma unroll
    for (int n = 0; n < 4; ++n) {
      int col = bcol + wc * 64 + n * 16 + lr;
      float bv = (EPI == EPI_BF16) ? 0.f : bias[col];
      #pragma unroll
      for (int j = 0; j < 4; ++j) {
        float v = acc[m][n][j];
        size_t off = (size_t)(row0 + j) * N + col;
        if (EPI == EPI_BF16) {
          ((__bf16*)Cout)[off] = (__bf16)v;
        } else if (EPI == EPI_F32_BIAS) {
          ((float*)Cout)[off] = v + bv;
        } else if (EPI == EPI_BF16_BIAS) {
          ((__bf16*)Cout)[off] = (__bf16)(v + bv);
        } else {
          float z = v + bv;
          ((__bf16*)Cout)[off] = (__bf16)(z / (1.f + __expf(-z)));
        }
      }
    }
  }
}

// ---------------- attention pieces ----------------
// All take a batch index from blockIdx.z (z=0 == per-batch pointers, validated path).

__global__ __launch_bounds__(256) void q_softmax(__bf16* __restrict__ qkv) {
  qkv += (size_t)blockIdx.z * 4096 * 3072;
  int wg = blockIdx.x * 4 + (threadIdx.x >> 6);
  int l = threadIdx.x & 63;
  int row = wg >> 4, h = wg & 15;
  __bf16* p = qkv + (size_t)row * 3072 + h * 64 + l;
  float v = (float)*p * 0.125f;
  float m = v;
  #pragma unroll
  for (int s = 32; s; s >>= 1) m = fmaxf(m, __shfl_xor(m, s));
  float e = __expf(v - m);
  float sum = e;
  #pragma unroll
  for (int s = 32; s; s >>= 1) sum += __shfl_xor(sum, s);
  *p = (__bf16)(e / sum);
}

__global__ __launch_bounds__(256) void k_exp(__bf16* __restrict__ qkv, float* __restrict__ S) {
  qkv += (size_t)blockIdx.z * 4096 * 3072;
  S   += (size_t)blockIdx.z * 1024;
  int c = blockIdx.x * 256 + threadIdx.x;
  int n0 = blockIdx.y * 128;
  float sum = 0.f;
  __bf16* base = qkv + (size_t)n0 * 3072 + 1024 + c;
  for (int i = 0; i < 128; ++i) {
    __bf16* p = base + (size_t)i * 3072;
    float e = __expf((float)*p);
    __bf16 eb = (__bf16)e;
    *p = eb;
    sum += (float)eb;
  }
  atomicAdd(&S[c], sum);
}

__global__ __launch_bounds__(256) void ctx_gemm(const __bf16* __restrict__ qkv,
                                                float* __restrict__ ctx) {
  qkv += (size_t)blockIdx.z * 4096 * 3072;
  ctx += (size_t)blockIdx.z * 16 * 4096;
  int h = blockIdx.x;
  int k0base = blockIdx.y * 1024;
  __shared__ __bf16 sQ[64 * 32];
  __shared__ __bf16 sK[64 * 32];
  int tid = threadIdx.x, w = tid >> 6, l = tid & 63;
  int lr = l & 15, lk = (l >> 4) * 8;
  int srow = tid >> 3, scol = (tid & 7) * 8;
  f32x4 acc[4] = {};

  for (int kc = 0; kc < 1024; kc += 32) {
    size_t grow = (size_t)(k0base + kc + srow) * 3072;
    bf16x8 qv = *(const bf16x8*)(qkv + grow + h * 64 + scol);
    bf16x8 kv = *(const bf16x8*)(qkv + grow + 1024 + h * 64 + scol);
    __syncthreads();
    #pragma unroll
    for (int j = 0; j < 8; ++j) {
      sQ[(scol + j) * 32 + srow] = qv[j];
      sK[(scol + j) * 32 + srow] = kv[j];
    }
    __syncthreads();
    bf16x8 a = *(const bf16x8*)(sQ + (w * 16 + lr) * 32 + lk);
    #pragma unroll
    for (int n = 0; n < 4; ++n) {
      bf16x8 bb = *(const bf16x8*)(sK + (n * 16 + lr) * 32 + lk);
      acc[n] = __builtin_amdgcn_mfma_f32_16x16x32_bf16(a, bb, acc[n], 0, 0, 0);
    }
  }
  float* cbase = ctx + (size_t)h * 64 * 64;
  #pragma unroll
  for (int n = 0; n < 4; ++n) {
    int col = n * 16 + lr;
    #pragma unroll
    for (int j = 0; j < 4; ++j) {
      int row = w * 16 + (l >> 4) * 4 + j;
      atomicAdd(cbase + row * 64 + col, acc[n][j]);
    }
  }
}

__global__ __launch_bounds__(256) void pv_gemm(const __bf16* __restrict__ qkv,
                                               const float* __restrict__ ctx,
                                               const float* __restrict__ S,
                                               __bf16* __restrict__ outpv) {
  qkv   += (size_t)blockIdx.z * 4096 * 3072;
  ctx   += (size_t)blockIdx.z * 16 * 4096;
  S     += (size_t)blockIdx.z * 1024;
  outpv += (size_t)blockIdx.z * 4096 * 1024;
  int h = blockIdx.y;
  int row0 = blockIdx.x * 128;
  __shared__ __bf16 sC[64 * 64];
  int tid = threadIdx.x;
  const float* cb = ctx + (size_t)h * 4096;
  for (int i = tid; i < 4096; i += 256) {
    int d = i >> 6, e = i & 63;
    sC[e * 64 + d] = (__bf16)cb[i];
  }
  __syncthreads();
  int w = tid >> 6, l = tid & 63;
  int lr = l & 15, lk = (l >> 4) * 8;
  f32x4 acc[2][4] = {};
  const __bf16* vbase = qkv + 2048 + h * 64;
  #pragma unroll
  for (int kk = 0; kk < 64; kk += 32) {
    #pragma unroll
    for (int m = 0; m < 2; ++m) {
      int r = row0 + w * 32 + m * 16 + lr;
      bf16x8 a = *(const bf16x8*)(vbase + (size_t)r * 3072 + kk + lk);
      #pragma unroll
      for (int n = 0; n < 4; ++n) {
        bf16x8 bb = *(const bf16x8*)(sC + (n * 16 + lr) * 64 + kk + lk);
        acc[m][n] = __builtin_amdgcn_mfma_f32_16x16x32_bf16(a, bb, acc[m][n], 0, 0, 0);
      }
    }
  }
  #pragma unroll
  for (int m = 0; m < 2; ++m) {
    int rb = row0 + w * 32 + m * 16 + (l >> 4) * 4;
    #pragma unroll
    for (int n = 0; n < 4; ++n) {
      int e = n * 16 + lr;
      float inv = 1.0f / S[h * 64 + e];
      #pragma unroll
      for (int j = 0; j < 4; ++j)
        outpv[(size_t)(rb + j) * 1024 + h * 64 + e] = (__bf16)(acc[m][n][j] * inv);
    }
  }
}

// ---------------- LayerNorm (row of 1024, bf16 in -> bf16 out) ----------------
__global__ __launch_bounds__(256) void layernorm_k(const __bf16* __restrict__ attn,
                                                   const float* __restrict__ g,
                                                   const float* __restrict__ beta,
                                                   __bf16* __restrict__ out) {
  int row = blockIdx.x;
  int t = threadIdx.x;
  bf16x4 v4 = *(const bf16x4*)(attn + (size_t)row * 1024 + t * 4);
  float v0 = (float)v4[0], v1 = (float)v4[1], v2 = (float)v4[2], v3 = (float)v4[3];
  float s = v0 + v1 + v2 + v3;
  float ss = v0 * v0 + v1 * v1 + v2 * v2 + v3 * v3;
  #pragma unroll
  for (int sh = 32; sh; sh >>= 1) { s += __shfl_xor(s, sh); ss += __shfl_xor(ss, sh); }
  __shared__ float red[8];
  int w = t >> 6, l = t & 63;
  if (l == 0) { red[w] = s; red[4 + w] = ss; }
  __syncthreads();
  s = red[0] + red[1] + red[2] + red[3];
  ss = red[4] + red[5] + red[6] + red[7];
  float mu = s * (1.f / 1024.f);
  float var = ss * (1.f / 1024.f) - mu * mu;
  float rstd = rsqrtf(var + 1e-5f);
  float4 gg = *(const float4*)(g + t * 4);
  float4 bb = *(const float4*)(beta + t * 4);
  bf16x4 o;
  o[0] = (__bf16)((v0 - mu) * rstd * gg.x + bb.x);
  o[1] = (__bf16)((v1 - mu) * rstd * gg.y + bb.y);
  o[2] = (__bf16)((v2 - mu) * rstd * gg.z + bb.z);
  o[3] = (__bf16)((v3 - mu) * rstd * gg.w + bb.w);
  *(bf16x4*)(out + (size_t)row * 1024 + t * 4) = o;
}

// ---------------- launch ----------------

extern "C" void kernel_launch(void* const* d_in, const int* in_sizes, int n_in,
                              void* d_out, int out_size, void* d_ws, size_t ws_size,
                              hipStream_t stream) {
  const float* x     = (const float*)d_in[0];
  const float* W_qkv = (const float*)d_in[1];
  const float* W_out = (const float*)d_in[2];
  const float* b_out = (const float*)d_in[3];
  const float* ln_g  = (const float*)d_in[4];
  const float* ln_b  = (const float*)d_in[5];
  const float* W1    = (const float*)d_in[6];
  const float* b1    = (const float*)d_in[7];
  const float* W2    = (const float*)d_in[8];
  const float* b2    = (const float*)d_in[9];

  char* ws = (char*)d_ws;
  size_t off = 0;
  auto alloc = [&](size_t bytes) { void* p = ws + off; off += (bytes + 255) & ~(size_t)255; return p; };

  __bf16* wqkvT = (__bf16*)alloc(3072ull * 1024 * 2);
  __bf16* woutT = (__bf16*)alloc(1024ull * 1024 * 2);
  __bf16* w1T   = (__bf16*)alloc(4096ull * 1024 * 2);
  __bf16* w2T   = (__bf16*)alloc(1024ull * 4096 * 2);

  cvt_wT<<<dim3(32, 96), dim3(32, 8), 0, stream>>>(W_qkv, wqkvT, 1024, 3072);
  cvt_wT<<<dim3(32, 32), dim3(32, 8), 0, stream>>>(W_out, woutT, 1024, 1024);
  cvt_wT<<<dim3(32, 128), dim3(32, 8), 0, stream>>>(W1, w1T, 1024, 4096);
  cvt_wT<<<dim3(128, 32), dim3(32, 8), 0, stream>>>(W2, w2T, 4096, 1024);

  const size_t FULL_NEED = 196ull << 20;

  if (ws_size >= FULL_NEED) {
    // ---------- FULL path ----------
    float*  Sctx  = (float*)alloc((4096ull + 4 * 16 * 4096) * 4);
    __bf16* xb    = (__bf16*)alloc(16384ull * 1024 * 2);
    __bf16* qkv   = (__bf16*)alloc(16384ull * 3072 * 2);
    __bf16* outpv = (__bf16*)alloc(16384ull * 1024 * 2);

    float* S   = Sctx;
    float* ctx = Sctx + 4096;
    __bf16* attn = (__bf16*)((char*)qkv + (64ull << 20));
    __bf16* hln  = xb;
    __bf16* ffn1 = qkv;

    cvt_f32_bf16<<<16384, 256, 0, stream>>>(x, xb, 16777216L);
    zero_f32<<<260, 256, 0, stream>>>(Sctx, 266240);

    gemm256<EPI_BF16><<<dim3(64, 12), 512, 0, stream>>>(xb, wqkvT, qkv, nullptr, 16384, 3072, 1024);
    q_softmax<<<dim3(16384, 1, 4), 256, 0, stream>>>(qkv);
    k_exp<<<dim3(4, 32, 4), 256, 0, stream>>>(qkv, S);
    ctx_gemm<<<dim3(16, 4, 4), 256, 0, stream>>>(qkv, ctx);
    pv_gemm<<<dim3(32, 16, 4), 256, 0, stream>>>(qkv, ctx, S, outpv);

    gemm256<EPI_BF16_BIAS><<<dim3(64, 4), 512, 0, stream>>>(outpv, woutT, attn, b_out, 16384, 1024, 1024);
    layernorm_k<<<16384, 256, 0, stream>>>(attn, ln_g, ln_b, hln);
    gemm256<EPI_BF16_SILU><<<dim3(64, 16), 512, 0, stream>>>(hln, w1T, ffn1, b1, 16384, 4096, 1024);
    gemm256<EPI_F32_BIAS><<<dim3(64, 4), 512, 0, stream>>>(ffn1, w2T, (float*)d_out, b2, 16384, 1024, 4096);
  } else {
    // ---------- CHUNKED fallback (~112 MiB) ----------
    float*  Sctx  = (float*)alloc(66560ull * 4);
    __bf16* xb    = (__bf16*)alloc(16384ull * 1024 * 2);
    __bf16* outpv = (__bf16*)alloc(16384ull * 1024 * 2);
    __bf16* qkv_b = (__bf16*)alloc(4096ull * 3072 * 2);

    float* S   = Sctx;
    float* ctx = Sctx + 1024;
    __bf16* attn = xb;
    __bf16* hln  = outpv;
    __bf16* fchunk = xb;

    cvt_f32_bf16<<<16384, 256, 0, stream>>>(x, xb, 16777216L);

    for (int b = 0; b < 4; ++b) {
      const __bf16* xb_b = xb + (size_t)b * 4096 * 1024;
      gemm256<EPI_BF16><<<dim3(16, 12), 512, 0, stream>>>(xb_b, wqkvT, qkv_b, nullptr, 4096, 3072, 1024);
      zero_f32<<<65, 256, 0, stream>>>(Sctx, 66560);
      q_softmax<<<dim3(16384, 1, 1), 256, 0, stream>>>(qkv_b);
      k_exp<<<dim3(4, 32, 1), 256, 0, stream>>>(qkv_b, S);
      ctx_gemm<<<dim3(16, 4, 1), 256, 0, stream>>>(qkv_b, ctx);
      pv_gemm<<<dim3(32, 16, 1), 256, 0, stream>>>(qkv_b, ctx, S, outpv + (size_t)b * 4096 * 1024);
    }

    gemm256<EPI_BF16_BIAS><<<dim3(64, 4), 512, 0, stream>>>(outpv, woutT, attn, b_out, 16384, 1024, 1024);
    layernorm_k<<<16384, 256, 0, stream>>>(attn, ln_g, ln_b, hln);

    for (int c = 0; c < 4; ++c) {
      const __bf16* h_c = hln + (size_t)c * 4096 * 1024;
      float* out_c = (float*)d_out + (size_t)c * 4096 * 1024;
      gemm256<EPI_BF16_SILU><<<dim3(16, 16), 512, 0, stream>>>(h_c, w1T, fchunk, b1, 4096, 4096, 1024);
      gemm256<EPI_F32_BIAS><<<dim3(16, 4), 512, 0, stream>>>(fchunk, w2T, out_c, b2, 4096, 1024, 4096);
    }
  }
}

// Round 11
// 584.120 us; speedup vs baseline: 1.0725x; 1.0725x over previous
//
#include <hip/hip_runtime.h>
#include <hip/hip_bf16.h>

typedef __bf16 bf16x8 __attribute__((ext_vector_type(8)));
typedef __bf16 bf16x4 __attribute__((ext_vector_type(4)));
typedef float  f32x4  __attribute__((ext_vector_type(4)));

#define GLOAD_LDS16(gp, lp) \
  __builtin_amdgcn_global_load_lds((const __attribute__((address_space(1))) void*)(gp), \
                                   (__attribute__((address_space(3))) void*)(lp), 16, 0, 0)
#define LGKM0 do { asm volatile("s_waitcnt lgkmcnt(0)" ::: "memory"); \
                   __builtin_amdgcn_sched_barrier(0); } while (0)

// ---------------- utility kernels ----------------

__global__ __launch_bounds__(256) void zero_f32(float* __restrict__ p, int n) {
  int i = (blockIdx.x * 256 + threadIdx.x) * 4;
  if (i < n) *(float4*)(p + i) = make_float4(0.f, 0.f, 0.f, 0.f);
}

__global__ __launch_bounds__(256) void cvt_f32_bf16(const float* __restrict__ in,
                                                    __bf16* __restrict__ out, long n) {
  long i = ((long)blockIdx.x * 256 + threadIdx.x) * 4;
  if (i >= n) return;
  float4 v = *(const float4*)(in + i);
  bf16x4 o;
  o[0] = (__bf16)v.x; o[1] = (__bf16)v.y; o[2] = (__bf16)v.z; o[3] = (__bf16)v.w;
  *(bf16x4*)(out + i) = o;
}

// W [K][N] f32 row-major  ->  WT [N][K] bf16 row-major
__global__ __launch_bounds__(256) void cvt_wT(const float* __restrict__ W,
                                              __bf16* __restrict__ WT, int K, int N) {
  __shared__ float t[32][33];
  int k0 = blockIdx.x * 32, n0 = blockIdx.y * 32;
  int tx = threadIdx.x, ty = threadIdx.y;   // block (32,8)
  #pragma unroll
  for (int i = 0; i < 32; i += 8)
    t[ty + i][tx] = W[(size_t)(k0 + ty + i) * N + n0 + tx];
  __syncthreads();
  #pragma unroll
  for (int i = 0; i < 32; i += 8)
    WT[(size_t)(n0 + ty + i) * K + k0 + tx] = (__bf16)t[tx][ty + i];
}

// ---- 256x256 GEMM, BK=64, 4 MFMA-phases/K-tile (round-8 kernel, race-screened) ----
// 512 threads (8 waves 2Mx4N), dbuf LDS 128 KiB. vmcnt(8) at p1/p3 only.
// Swizzle: linear LDS dest; source octet o^((row>>1)&3); same involution on read.

enum { EPI_BF16 = 0, EPI_F32_BIAS = 1, EPI_BF16_SILU = 2, EPI_BF16_BIAS = 3 };

template <int EPI>
__global__ __launch_bounds__(512, 1)
void gemm256(const __bf16* __restrict__ A, const __bf16* __restrict__ B,
             void* __restrict__ Cout, const float* __restrict__ bias,
             int M, int N, int K) {
  __shared__ __bf16 lds[65536];   // 128 KiB
  const int tid = threadIdx.x;
  const int w = tid >> 6, l = tid & 63;
  const int brow = blockIdx.x * 256;
  const int bcol = blockIdx.y * 256;
  const int wr = w >> 2, wc = w & 3;            // wave grid 2x4
  const int lr = l & 15;
  const int rdo8 = ((l >> 4) ^ ((lr >> 1) & 3)) << 3;   // swizzled read octet
  const int NT = K >> 6;                         // BK = 64

  const int aoff = (wr * 128 + lr) * 32 + rdo8;
  const int boff = 16384 + (wc * 64 + lr) * 32 + rdo8;

  const int srow = w * 16 + (l >> 2);
  const int soct8 = ((l & 3) ^ ((l >> 3) & 3)) * 8;
  const __bf16* pA0 = A + (size_t)(brow + srow) * K + soct8;
  const __bf16* pA1 = A + (size_t)(brow + 128 + srow) * K + soct8;
  const __bf16* pB0 = B + (size_t)(bcol + srow) * K + soct8;
  const __bf16* pB1 = B + (size_t)(bcol + 128 + srow) * K + soct8;

  auto stageA = [&](int k, int Tt) {
    size_t cofs = (size_t)Tt * 64 + k * 32;
    __bf16* d = lds + (Tt & 1) * 32768 + k * 8192 + w * 512;
    GLOAD_LDS16(pA0 + cofs, d);
    GLOAD_LDS16(pA1 + cofs, d + 4096);
  };
  auto stageB = [&](int k, int Tt) {
    size_t cofs = (size_t)Tt * 64 + k * 32;
    __bf16* d = lds + (Tt & 1) * 32768 + 16384 + k * 8192 + w * 512;
    GLOAD_LDS16(pB0 + cofs, d);
    GLOAD_LDS16(pB1 + cofs, d + 4096);
  };

  f32x4 acc[8][4] = {};
  bf16x8 afr[4], bfr[4];

  stageA(0, 0); stageB(0, 0);
  stageA(1, 0); stageB(1, 0);
  stageA(0, 1); stageB(0, 1);

  for (int T = 0; T < NT; ++T) {
    const int buf = (T & 1) * 32768;
    const bool s1 = (T + 1 < NT), s2 = (T + 2 < NT);

    // ---- p1: (mh0, kk0) ----
    if (s1) asm volatile("s_waitcnt vmcnt(8)" ::: "memory");
    else    asm volatile("s_waitcnt vmcnt(4)" ::: "memory");
    __builtin_amdgcn_s_barrier();
    {
      const __bf16* pb = lds + buf + boff;
      const __bf16* pa = lds + buf + aoff;
      #pragma unroll
      for (int n = 0; n < 4; ++n) bfr[n] = *(const bf16x8*)(pb + n * 512);
      #pragma unroll
      for (int m = 0; m < 4; ++m) afr[m] = *(const bf16x8*)(pa + m * 512);
      if (s1) stageA(1, T + 1);
      LGKM0;
      __builtin_amdgcn_s_setprio(1);
      #pragma unroll
      for (int m = 0; m < 4; ++m)
        #pragma unroll
        for (int n = 0; n < 4; ++n)
          acc[m][n] = __builtin_amdgcn_mfma_f32_16x16x32_bf16(afr[m], bfr[n], acc[m][n], 0, 0, 0);
      __builtin_amdgcn_s_setprio(0);
    }

    // ---- p2: (mh1, kk0), reuse bfr ----
    __builtin_amdgcn_s_barrier();
    {
      const __bf16* pa = lds + buf + aoff + 2048;
      #pragma unroll
      for (int m = 0; m < 4; ++m) afr[m] = *(const bf16x8*)(pa + m * 512);
      if (s1) stageB(1, T + 1);
      LGKM0;
      __builtin_amdgcn_s_setprio(1);
      #pragma unroll
      for (int m = 0; m < 4; ++m)
        #pragma unroll
        for (int n = 0; n < 4; ++n)
          acc[m + 4][n] = __builtin_amdgcn_mfma_f32_16x16x32_bf16(afr[m], bfr[n], acc[m + 4][n], 0, 0, 0);
      __builtin_amdgcn_s_setprio(0);
    }

    // ---- p3: (mh0, kk1) ----
    if (s1) asm volatile("s_waitcnt vmcnt(8)" ::: "memory");
    else    asm volatile("s_waitcnt vmcnt(0)" ::: "memory");
    __builtin_amdgcn_s_barrier();
    {
      const __bf16* pb = lds + buf + 8192 + boff;
      const __bf16* pa = lds + buf + 8192 + aoff;
      #pragma unroll
      for (int n = 0; n < 4; ++n) bfr[n] = *(const bf16x8*)(pb + n * 512);
      #pragma unroll
      for (int m = 0; m < 4; ++m) afr[m] = *(const bf16x8*)(pa + m * 512);
      if (s2) stageA(0, T + 2);
      LGKM0;
      __builtin_amdgcn_s_setprio(1);
      #pragma unroll
      for (int m = 0; m < 4; ++m)
        #pragma unroll
        for (int n = 0; n < 4; ++n)
          acc[m][n] = __builtin_amdgcn_mfma_f32_16x16x32_bf16(afr[m], bfr[n], acc[m][n], 0, 0, 0);
      __builtin_amdgcn_s_setprio(0);
    }

    // ---- p4: (mh1, kk1), reuse bfr ----
    __builtin_amdgcn_s_barrier();
    {
      const __bf16* pa = lds + buf + 8192 + aoff + 2048;
      #pragma unroll
      for (int m = 0; m < 4; ++m) afr[m] = *(const bf16x8*)(pa + m * 512);
      if (s2) stageB(0, T + 2);
      LGKM0;
      __builtin_amdgcn_s_setprio(1);
      #pragma unroll
      for (int m = 0; m < 4; ++m)
        #pragma unroll
        for (int n = 0; n < 4; ++n)
          acc[m + 4][n] = __builtin_amdgcn_mfma_f32_16x16x32_bf16(afr[m], bfr[n], acc[m + 4][n], 0, 0, 0);
      __builtin_amdgcn_s_setprio(0);
    }
  }

  #pragma unroll
  for (int m = 0; m < 8; ++m) {
    int row0 = brow + wr * 128 + m * 16 + (l >> 4) * 4;
    #pragma unroll
    for (int n = 0; n < 4; ++n) {
      int col = bcol + wc * 64 + n * 16 + lr;
      float bv = (EPI == EPI_BF16) ? 0.f : bias[col];
      #pragma unroll
      for (int j = 0; j < 4; ++j) {
        float v = acc[m][n][j];
        size_t off = (size_t)(row0 + j) * N + col;
        if (EPI == EPI_BF16) {
          ((__bf16*)Cout)[off] = (__bf16)v;
        } else if (EPI == EPI_F32_BIAS) {
          ((float*)Cout)[off] = v + bv;
        } else if (EPI == EPI_BF16_BIAS) {
          ((__bf16*)Cout)[off] = (__bf16)(v + bv);
        } else {
          float z = v + bv;
          ((__bf16*)Cout)[off] = (__bf16)(z / (1.f + __expf(-z)));
        }
      }
    }
  }
}

// ---------------- attention pieces ----------------
// All take a batch index from blockIdx.z (z=0 == per-batch pointers, validated path).

__global__ __launch_bounds__(256) void q_softmax(__bf16* __restrict__ qkv) {
  qkv += (size_t)blockIdx.z * 4096 * 3072;
  int wg = blockIdx.x * 4 + (threadIdx.x >> 6);
  int l = threadIdx.x & 63;
  int row = wg >> 4, h = wg & 15;
  __bf16* p = qkv + (size_t)row * 3072 + h * 64 + l;
  float v = (float)*p * 0.125f;
  float m = v;
  #pragma unroll
  for (int s = 32; s; s >>= 1) m = fmaxf(m, __shfl_xor(m, s));
  float e = __expf(v - m);
  float sum = e;
  #pragma unroll
  for (int s = 32; s; s >>= 1) sum += __shfl_xor(sum, s);
  *p = (__bf16)(e / sum);
}

__global__ __launch_bounds__(256) void k_exp(__bf16* __restrict__ qkv, float* __restrict__ S) {
  qkv += (size_t)blockIdx.z * 4096 * 3072;
  S   += (size_t)blockIdx.z * 1024;
  int c = blockIdx.x * 256 + threadIdx.x;
  int n0 = blockIdx.y * 128;
  float sum = 0.f;
  __bf16* base = qkv + (size_t)n0 * 3072 + 1024 + c;
  for (int i = 0; i < 128; ++i) {
    __bf16* p = base + (size_t)i * 3072;
    float e = __expf((float)*p);
    __bf16 eb = (__bf16)e;
    *p = eb;
    sum += (float)eb;
  }
  atomicAdd(&S[c], sum);
}

__global__ __launch_bounds__(256) void ctx_gemm(const __bf16* __restrict__ qkv,
                                                float* __restrict__ ctx) {
  qkv += (size_t)blockIdx.z * 4096 * 3072;
  ctx += (size_t)blockIdx.z * 16 * 4096;
  int h = blockIdx.x;
  int k0base = blockIdx.y * 1024;
  __shared__ __bf16 sQ[64 * 32];
  __shared__ __bf16 sK[64 * 32];
  int tid = threadIdx.x, w = tid >> 6, l = tid & 63;
  int lr = l & 15, lk = (l >> 4) * 8;
  int srow = tid >> 3, scol = (tid & 7) * 8;
  f32x4 acc[4] = {};

  for (int kc = 0; kc < 1024; kc += 32) {
    size_t grow = (size_t)(k0base + kc + srow) * 3072;
    bf16x8 qv = *(const bf16x8*)(qkv + grow + h * 64 + scol);
    bf16x8 kv = *(const bf16x8*)(qkv + grow + 1024 + h * 64 + scol);
    __syncthreads();
    #pragma unroll
    for (int j = 0; j < 8; ++j) {
      sQ[(scol + j) * 32 + srow] = qv[j];
      sK[(scol + j) * 32 + srow] = kv[j];
    }
    __syncthreads();
    bf16x8 a = *(const bf16x8*)(sQ + (w * 16 + lr) * 32 + lk);
    #pragma unroll
    for (int n = 0; n < 4; ++n) {
      bf16x8 bb = *(const bf16x8*)(sK + (n * 16 + lr) * 32 + lk);
      acc[n] = __builtin_amdgcn_mfma_f32_16x16x32_bf16(a, bb, acc[n], 0, 0, 0);
    }
  }
  float* cbase = ctx + (size_t)h * 64 * 64;
  #pragma unroll
  for (int n = 0; n < 4; ++n) {
    int col = n * 16 + lr;
    #pragma unroll
    for (int j = 0; j < 4; ++j) {
      int row = w * 16 + (l >> 4) * 4 + j;
      atomicAdd(cbase + row * 64 + col, acc[n][j]);
    }
  }
}

__global__ __launch_bounds__(256) void pv_gemm(const __bf16* __restrict__ qkv,
                                               const float* __restrict__ ctx,
                                               const float* __restrict__ S,
                                               __bf16* __restrict__ outpv) {
  qkv   += (size_t)blockIdx.z * 4096 * 3072;
  ctx   += (size_t)blockIdx.z * 16 * 4096;
  S     += (size_t)blockIdx.z * 1024;
  outpv += (size_t)blockIdx.z * 4096 * 1024;
  int h = blockIdx.y;
  int row0 = blockIdx.x * 128;
  __shared__ __bf16 sC[64 * 64];
  int tid = threadIdx.x;
  const float* cb = ctx + (size_t)h * 4096;
  for (int i = tid; i < 4096; i += 256) {
    int d = i >> 6, e = i & 63;
    sC[e * 64 + d] = (__bf16)cb[i];
  }
  __syncthreads();
  int w = tid >> 6, l = tid & 63;
  int lr = l & 15, lk = (l >> 4) * 8;
  f32x4 acc[2][4] = {};
  const __bf16* vbase = qkv + 2048 + h * 64;
  #pragma unroll
  for (int kk = 0; kk < 64; kk += 32) {
    #pragma unroll
    for (int m = 0; m < 2; ++m) {
      int r = row0 + w * 32 + m * 16 + lr;
      bf16x8 a = *(const bf16x8*)(vbase + (size_t)r * 3072 + kk + lk);
      #pragma unroll
      for (int n = 0; n < 4; ++n) {
        bf16x8 bb = *(const bf16x8*)(sC + (n * 16 + lr) * 64 + kk + lk);
        acc[m][n] = __builtin_amdgcn_mfma_f32_16x16x32_bf16(a, bb, acc[m][n], 0, 0, 0);
      }
    }
  }
  #pragma unroll
  for (int m = 0; m < 2; ++m) {
    int rb = row0 + w * 32 + m * 16 + (l >> 4) * 4;
    #pragma unroll
    for (int n = 0; n < 4; ++n) {
      int e = n * 16 + lr;
      float inv = 1.0f / S[h * 64 + e];
      #pragma unroll
      for (int j = 0; j < 4; ++j)
        outpv[(size_t)(rb + j) * 1024 + h * 64 + e] = (__bf16)(acc[m][n][j] * inv);
    }
  }
}

// ---------------- LayerNorm (row of 1024, bf16 in -> bf16 out) ----------------
__global__ __launch_bounds__(256) void layernorm_k(const __bf16* __restrict__ attn,
                                                   const float* __restrict__ g,
                                                   const float* __restrict__ beta,
                                                   __bf16* __restrict__ out) {
  int row = blockIdx.x;
  int t = threadIdx.x;
  bf16x4 v4 = *(const bf16x4*)(attn + (size_t)row * 1024 + t * 4);
  float v0 = (float)v4[0], v1 = (float)v4[1], v2 = (float)v4[2], v3 = (float)v4[3];
  float s = v0 + v1 + v2 + v3;
  float ss = v0 * v0 + v1 * v1 + v2 * v2 + v3 * v3;
  #pragma unroll
  for (int sh = 32; sh; sh >>= 1) { s += __shfl_xor(s, sh); ss += __shfl_xor(ss, sh); }
  __shared__ float red[8];
  int w = t >> 6, l = t & 63;
  if (l == 0) { red[w] = s; red[4 + w] = ss; }
  __syncthreads();
  s = red[0] + red[1] + red[2] + red[3];
  ss = red[4] + red[5] + red[6] + red[7];
  float mu = s * (1.f / 1024.f);
  float var = ss * (1.f / 1024.f) - mu * mu;
  float rstd = rsqrtf(var + 1e-5f);
  float4 gg = *(const float4*)(g + t * 4);
  float4 bb = *(const float4*)(beta + t * 4);
  bf16x4 o;
  o[0] = (__bf16)((v0 - mu) * rstd * gg.x + bb.x);
  o[1] = (__bf16)((v1 - mu) * rstd * gg.y + bb.y);
  o[2] = (__bf16)((v2 - mu) * rstd * gg.z + bb.z);
  o[3] = (__bf16)((v3 - mu) * rstd * gg.w + bb.w);
  *(bf16x4*)(out + (size_t)row * 1024 + t * 4) = o;
}

// ---------------- launch ----------------

extern "C" void kernel_launch(void* const* d_in, const int* in_sizes, int n_in,
                              void* d_out, int out_size, void* d_ws, size_t ws_size,
                              hipStream_t stream) {
  const float* x     = (const float*)d_in[0];
  const float* W_qkv = (const float*)d_in[1];
  const float* W_out = (const float*)d_in[2];
  const float* b_out = (const float*)d_in[3];
  const float* ln_g  = (const float*)d_in[4];
  const float* ln_b  = (const float*)d_in[5];
  const float* W1    = (const float*)d_in[6];
  const float* b1    = (const float*)d_in[7];
  const float* W2    = (const float*)d_in[8];
  const float* b2    = (const float*)d_in[9];

  char* ws = (char*)d_ws;
  size_t off = 0;
  auto alloc = [&](size_t bytes) { void* p = ws + off; off += (bytes + 255) & ~(size_t)255; return p; };

  __bf16* wqkvT = (__bf16*)alloc(3072ull * 1024 * 2);
  __bf16* woutT = (__bf16*)alloc(1024ull * 1024 * 2);
  __bf16* w1T   = (__bf16*)alloc(4096ull * 1024 * 2);
  __bf16* w2T   = (__bf16*)alloc(1024ull * 4096 * 2);

  cvt_wT<<<dim3(32, 96), dim3(32, 8), 0, stream>>>(W_qkv, wqkvT, 1024, 3072);
  cvt_wT<<<dim3(32, 32), dim3(32, 8), 0, stream>>>(W_out, woutT, 1024, 1024);
  cvt_wT<<<dim3(32, 128), dim3(32, 8), 0, stream>>>(W1, w1T, 1024, 4096);
  cvt_wT<<<dim3(128, 32), dim3(32, 8), 0, stream>>>(W2, w2T, 4096, 1024);

  const size_t FULL_NEED = 196ull << 20;

  if (ws_size >= FULL_NEED) {
    // ---------- FULL path ----------
    float*  Sctx  = (float*)alloc((4096ull + 4 * 16 * 4096) * 4);
    __bf16* xb    = (__bf16*)alloc(16384ull * 1024 * 2);
    __bf16* qkv   = (__bf16*)alloc(16384ull * 3072 * 2);
    __bf16* outpv = (__bf16*)alloc(16384ull * 1024 * 2);

    float* S   = Sctx;
    float* ctx = Sctx + 4096;
    __bf16* attn = (__bf16*)((char*)qkv + (64ull << 20));
    __bf16* hln  = xb;
    __bf16* ffn1 = qkv;

    cvt_f32_bf16<<<16384, 256, 0, stream>>>(x, xb, 16777216L);
    zero_f32<<<260, 256, 0, stream>>>(Sctx, 266240);

    gemm256<EPI_BF16><<<dim3(64, 12), 512, 0, stream>>>(xb, wqkvT, qkv, nullptr, 16384, 3072, 1024);
    q_softmax<<<dim3(16384, 1, 4), 256, 0, stream>>>(qkv);
    k_exp<<<dim3(4, 32, 4), 256, 0, stream>>>(qkv, S);
    ctx_gemm<<<dim3(16, 4, 4), 256, 0, stream>>>(qkv, ctx);
    pv_gemm<<<dim3(32, 16, 4), 256, 0, stream>>>(qkv, ctx, S, outpv);

    gemm256<EPI_BF16_BIAS><<<dim3(64, 4), 512, 0, stream>>>(outpv, woutT, attn, b_out, 16384, 1024, 1024);
    layernorm_k<<<16384, 256, 0, stream>>>(attn, ln_g, ln_b, hln);
    gemm256<EPI_BF16_SILU><<<dim3(64, 16), 512, 0, stream>>>(hln, w1T, ffn1, b1, 16384, 4096, 1024);
    gemm256<EPI_F32_BIAS><<<dim3(64, 4), 512, 0, stream>>>(ffn1, w2T, (float*)d_out, b2, 16384, 1024, 4096);
  } else {
    // ---------- CHUNKED fallback (~112 MiB) ----------
    float*  Sctx  = (float*)alloc(66560ull * 4);
    __bf16* xb    = (__bf16*)alloc(16384ull * 1024 * 2);
    __bf16* outpv = (__bf16*)alloc(16384ull * 1024 * 2);
    __bf16* qkv_b = (__bf16*)alloc(4096ull * 3072 * 2);

    float* S   = Sctx;
    float* ctx = Sctx + 1024;
    __bf16* attn = xb;
    __bf16* hln  = outpv;
    __bf16* fchunk = xb;

    cvt_f32_bf16<<<16384, 256, 0, stream>>>(x, xb, 16777216L);

    for (int b = 0; b < 4; ++b) {
      const __bf16* xb_b = xb + (size_t)b * 4096 * 1024;
      gemm256<EPI_BF16><<<dim3(16, 12), 512, 0, stream>>>(xb_b, wqkvT, qkv_b, nullptr, 4096, 3072, 1024);
      zero_f32<<<65, 256, 0, stream>>>(Sctx, 66560);
      q_softmax<<<dim3(16384, 1, 1), 256, 0, stream>>>(qkv_b);
      k_exp<<<dim3(4, 32, 1), 256, 0, stream>>>(qkv_b, S);
      ctx_gemm<<<dim3(16, 4, 1), 256, 0, stream>>>(qkv_b, ctx);
      pv_gemm<<<dim3(32, 16, 1), 256, 0, stream>>>(qkv_b, ctx, S, outpv + (size_t)b * 4096 * 1024);
    }

    gemm256<EPI_BF16_BIAS><<<dim3(64, 4), 512, 0, stream>>>(outpv, woutT, attn, b_out, 16384, 1024, 1024);
    layernorm_k<<<16384, 256, 0, stream>>>(attn, ln_g, ln_b, hln);

    for (int c = 0; c < 4; ++c) {
      const __bf16* h_c = hln + (size_t)c * 4096 * 1024;
      float* out_c = (float*)d_out + (size_t)c * 4096 * 1024;
      gemm256<EPI_BF16_SILU><<<dim3(16, 16), 512, 0, stream>>>(h_c, w1T, fchunk, b1, 4096, 4096, 1024);
      gemm256<EPI_F32_BIAS><<<dim3(16, 4), 512, 0, stream>>>(fchunk, w2T, out_c, b2, 4096, 1024, 4096);
    }
  }
}

// Round 12
// 544.291 us; speedup vs baseline: 1.1509x; 1.0732x over previous
//
#include <hip/hip_runtime.h>
#include <hip/hip_bf16.h>

typedef __bf16 bf16x8 __attribute__((ext_vector_type(8)));
typedef __bf16 bf16x4 __attribute__((ext_vector_type(4)));
typedef float  f32x4  __attribute__((ext_vector_type(4)));

#define GLOAD_LDS16(gp, lp) \
  __builtin_amdgcn_global_load_lds((const __attribute__((address_space(1))) void*)(gp), \
                                   (__attribute__((address_space(3))) void*)(lp), 16, 0, 0)
#define LGKM0 do { asm volatile("s_waitcnt lgkmcnt(0)" ::: "memory"); \
                   __builtin_amdgcn_sched_barrier(0); } while (0)

// ---------------- utility kernels ----------------

__global__ __launch_bounds__(256) void zero_f32(float* __restrict__ p, int n) {
  int i = (blockIdx.x * 256 + threadIdx.x) * 4;
  if (i < n) *(float4*)(p + i) = make_float4(0.f, 0.f, 0.f, 0.f);
}

__global__ __launch_bounds__(256) void cvt_f32_bf16(const float* __restrict__ in,
                                                    __bf16* __restrict__ out, long n) {
  long i = ((long)blockIdx.x * 256 + threadIdx.x) * 4;
  if (i >= n) return;
  float4 v = *(const float4*)(in + i);
  bf16x4 o;
  o[0] = (__bf16)v.x; o[1] = (__bf16)v.y; o[2] = (__bf16)v.z; o[3] = (__bf16)v.w;
  *(bf16x4*)(out + i) = o;
}

// W [K][N] f32 row-major  ->  WT [N][K] bf16 row-major
__global__ __launch_bounds__(256) void cvt_wT(const float* __restrict__ W,
                                              __bf16* __restrict__ WT, int K, int N) {
  __shared__ float t[32][33];
  int k0 = blockIdx.x * 32, n0 = blockIdx.y * 32;
  int tx = threadIdx.x, ty = threadIdx.y;   // block (32,8)
  #pragma unroll
  for (int i = 0; i < 32; i += 8)
    t[ty + i][tx] = W[(size_t)(k0 + ty + i) * N + n0 + tx];
  __syncthreads();
  #pragma unroll
  for (int i = 0; i < 32; i += 8)
    WT[(size_t)(n0 + ty + i) * K + k0 + tx] = (__bf16)t[tx][ty + i];
}

// ---- 256x256 GEMM, BK=64, 4 MFMA-phases/K-tile (race-screened r8 loop) ----
// 512 threads (8 waves 2Mx4N), dbuf LDS 128 KiB. vmcnt(8) at p1/p3 only.
// Swizzle: linear LDS dest; source octet o^((row>>1)&3); same involution on read.
// EPI_QKV: fused q-softmax (head dim lives in one wave: 4 regs x 16 lanes) and
// k-exp + column sums (atomicAdd once per col per block) in the epilogue.

enum { EPI_BF16 = 0, EPI_F32_BIAS = 1, EPI_BF16_SILU = 2, EPI_BF16_BIAS = 3, EPI_QKV = 4 };

template <int EPI>
__global__ __launch_bounds__(512, 1)
void gemm256(const __bf16* __restrict__ A, const __bf16* __restrict__ B,
             void* __restrict__ Cout, const float* __restrict__ bias,
             int M, int N, int K, float* __restrict__ Sq) {
  __shared__ __bf16 lds[65536];   // 128 KiB
  const int tid = threadIdx.x;
  const int w = tid >> 6, l = tid & 63;
  const int brow = blockIdx.x * 256;
  const int bcol = blockIdx.y * 256;
  const int wr = w >> 2, wc = w & 3;            // wave grid 2x4
  const int lr = l & 15;
  const int rdo8 = ((l >> 4) ^ ((lr >> 1) & 3)) << 3;   // swizzled read octet
  const int NT = K >> 6;                         // BK = 64

  const int aoff = (wr * 128 + lr) * 32 + rdo8;
  const int boff = 16384 + (wc * 64 + lr) * 32 + rdo8;

  const int srow = w * 16 + (l >> 2);
  const int soct8 = ((l & 3) ^ ((l >> 3) & 3)) * 8;
  const __bf16* pA0 = A + (size_t)(brow + srow) * K + soct8;
  const __bf16* pA1 = A + (size_t)(brow + 128 + srow) * K + soct8;
  const __bf16* pB0 = B + (size_t)(bcol + srow) * K + soct8;
  const __bf16* pB1 = B + (size_t)(bcol + 128 + srow) * K + soct8;

  auto stageA = [&](int k, int Tt) {
    size_t cofs = (size_t)Tt * 64 + k * 32;
    __bf16* d = lds + (Tt & 1) * 32768 + k * 8192 + w * 512;
    GLOAD_LDS16(pA0 + cofs, d);
    GLOAD_LDS16(pA1 + cofs, d + 4096);
  };
  auto stageB = [&](int k, int Tt) {
    size_t cofs = (size_t)Tt * 64 + k * 32;
    __bf16* d = lds + (Tt & 1) * 32768 + 16384 + k * 8192 + w * 512;
    GLOAD_LDS16(pB0 + cofs, d);
    GLOAD_LDS16(pB1 + cofs, d + 4096);
  };

  f32x4 acc[8][4] = {};
  bf16x8 afr[4], bfr[4];

  stageA(0, 0); stageB(0, 0);
  stageA(1, 0); stageB(1, 0);
  stageA(0, 1); stageB(0, 1);

  for (int T = 0; T < NT; ++T) {
    const int buf = (T & 1) * 32768;
    const bool s1 = (T + 1 < NT), s2 = (T + 2 < NT);

    // ---- p1: (mh0, kk0) ----
    if (s1) asm volatile("s_waitcnt vmcnt(8)" ::: "memory");
    else    asm volatile("s_waitcnt vmcnt(4)" ::: "memory");
    __builtin_amdgcn_s_barrier();
    {
      const __bf16* pb = lds + buf + boff;
      const __bf16* pa = lds + buf + aoff;
      #pragma unroll
      for (int n = 0; n < 4; ++n) bfr[n] = *(const bf16x8*)(pb + n * 512);
      #pragma unroll
      for (int m = 0; m < 4; ++m) afr[m] = *(const bf16x8*)(pa + m * 512);
      if (s1) stageA(1, T + 1);
      LGKM0;
      __builtin_amdgcn_s_setprio(1);
      #pragma unroll
      for (int m = 0; m < 4; ++m)
        #pragma unroll
        for (int n = 0; n < 4; ++n)
          acc[m][n] = __builtin_amdgcn_mfma_f32_16x16x32_bf16(afr[m], bfr[n], acc[m][n], 0, 0, 0);
      __builtin_amdgcn_s_setprio(0);
    }

    // ---- p2: (mh1, kk0), reuse bfr ----
    __builtin_amdgcn_s_barrier();
    {
      const __bf16* pa = lds + buf + aoff + 2048;
      #pragma unroll
      for (int m = 0; m < 4; ++m) afr[m] = *(const bf16x8*)(pa + m * 512);
      if (s1) stageB(1, T + 1);
      LGKM0;
      __builtin_amdgcn_s_setprio(1);
      #pragma unroll
      for (int m = 0; m < 4; ++m)
        #pragma unroll
        for (int n = 0; n < 4; ++n)
          acc[m + 4][n] = __builtin_amdgcn_mfma_f32_16x16x32_bf16(afr[m], bfr[n], acc[m + 4][n], 0, 0, 0);
      __builtin_amdgcn_s_setprio(0);
    }

    // ---- p3: (mh0, kk1) ----
    if (s1) asm volatile("s_waitcnt vmcnt(8)" ::: "memory");
    else    asm volatile("s_waitcnt vmcnt(0)" ::: "memory");
    __builtin_amdgcn_s_barrier();
    {
      const __bf16* pb = lds + buf + 8192 + boff;
      const __bf16* pa = lds + buf + 8192 + aoff;
      #pragma unroll
      for (int n = 0; n < 4; ++n) bfr[n] = *(const bf16x8*)(pb + n * 512);
      #pragma unroll
      for (int m = 0; m < 4; ++m) afr[m] = *(const bf16x8*)(pa + m * 512);
      if (s2) stageA(0, T + 2);
      LGKM0;
      __builtin_amdgcn_s_setprio(1);
      #pragma unroll
      for (int m = 0; m < 4; ++m)
        #pragma unroll
        for (int n = 0; n < 4; ++n)
          acc[m][n] = __builtin_amdgcn_mfma_f32_16x16x32_bf16(afr[m], bfr[n], acc[m][n], 0, 0, 0);
      __builtin_amdgcn_s_setprio(0);
    }

    // ---- p4: (mh1, kk1), reuse bfr ----
    __builtin_amdgcn_s_barrier();
    {
      const __bf16* pa = lds + buf + 8192 + aoff + 2048;
      #pragma unroll
      for (int m = 0; m < 4; ++m) afr[m] = *(const bf16x8*)(pa + m * 512);
      if (s2) stageB(0, T + 2);
      LGKM0;
      __builtin_amdgcn_s_setprio(1);
      #pragma unroll
      for (int m = 0; m < 4; ++m)
        #pragma unroll
        for (int n = 0; n < 4; ++n)
          acc[m + 4][n] = __builtin_amdgcn_mfma_f32_16x16x32_bf16(afr[m], bfr[n], acc[m + 4][n], 0, 0, 0);
      __builtin_amdgcn_s_setprio(0);
    }
  }

  // ---------------- epilogue ----------------
  if (EPI == EPI_QKV) {
    const int creg = bcol + wc * 64;     // wave col base (one 64-col head span)
    const int region = creg >> 10;       // 0=q, 1=k, 2=v
    if (region == 0) {
      // fused q-softmax over head dim (64 cols = 4 regs x 16 lanes)
      #pragma unroll
      for (int m = 0; m < 8; ++m) {
        int row0 = brow + wr * 128 + m * 16 + (l >> 4) * 4;
        #pragma unroll
        for (int j = 0; j < 4; ++j) {
          float v0 = acc[m][0][j] * 0.125f, v1 = acc[m][1][j] * 0.125f;
          float v2 = acc[m][2][j] * 0.125f, v3 = acc[m][3][j] * 0.125f;
          float mx = fmaxf(fmaxf(v0, v1), fmaxf(v2, v3));
          #pragma unroll
          for (int s = 1; s < 16; s <<= 1) mx = fmaxf(mx, __shfl_xor(mx, s));
          float e0 = __expf(v0 - mx), e1 = __expf(v1 - mx);
          float e2 = __expf(v2 - mx), e3 = __expf(v3 - mx);
          float sum = e0 + e1 + e2 + e3;
          #pragma unroll
          for (int s = 1; s < 16; s <<= 1) sum += __shfl_xor(sum, s);
          float inv = 1.f / sum;
          size_t ro = (size_t)(row0 + j) * N + creg + lr;
          ((__bf16*)Cout)[ro]      = (__bf16)(e0 * inv);
          ((__bf16*)Cout)[ro + 16] = (__bf16)(e1 * inv);
          ((__bf16*)Cout)[ro + 32] = (__bf16)(e2 * inv);
          ((__bf16*)Cout)[ro + 48] = (__bf16)(e3 * inv);
        }
      }
    } else if (region == 1) {
      // fused k-exp + column sums
      const int batch = brow >> 12;
      float csum[4] = {0.f, 0.f, 0.f, 0.f};
      #pragma unroll
      for (int m = 0; m < 8; ++m) {
        int row0 = brow + wr * 128 + m * 16 + (l >> 4) * 4;
        #pragma unroll
        for (int n = 0; n < 4; ++n) {
          int col = creg + n * 16 + lr;
          #pragma unroll
          for (int j = 0; j < 4; ++j) {
            float e = __expf(acc[m][n][j]);
            __bf16 eb = (__bf16)e;
            ((__bf16*)Cout)[(size_t)(row0 + j) * N + col] = eb;
            csum[n] += (float)eb;
          }
        }
      }
      #pragma unroll
      for (int n = 0; n < 4; ++n) {
        csum[n] += __shfl_xor(csum[n], 16);
        csum[n] += __shfl_xor(csum[n], 32);
      }
      if ((l >> 4) == 0) {
        #pragma unroll
        for (int n = 0; n < 4; ++n)
          atomicAdd(&Sq[batch * 1024 + (creg - 1024) + n * 16 + lr], csum[n]);
      }
    } else {
      // v region: plain bf16 store
      #pragma unroll
      for (int m = 0; m < 8; ++m) {
        int row0 = brow + wr * 128 + m * 16 + (l >> 4) * 4;
        #pragma unroll
        for (int n = 0; n < 4; ++n) {
          int col = creg + n * 16 + lr;
          #pragma unroll
          for (int j = 0; j < 4; ++j)
            ((__bf16*)Cout)[(size_t)(row0 + j) * N + col] = (__bf16)acc[m][n][j];
        }
      }
    }
  } else {
    #pragma unroll
    for (int m = 0; m < 8; ++m) {
      int row0 = brow + wr * 128 + m * 16 + (l >> 4) * 4;
      #pragma unroll
      for (int n = 0; n < 4; ++n) {
        int col = bcol + wc * 64 + n * 16 + lr;
        float bv = (EPI == EPI_BF16) ? 0.f : bias[col];
        #pragma unroll
        for (int j = 0; j < 4; ++j) {
          float v = acc[m][n][j];
          size_t off = (size_t)(row0 + j) * N + col;
          if (EPI == EPI_BF16) {
            ((__bf16*)Cout)[off] = (__bf16)v;
          } else if (EPI == EPI_F32_BIAS) {
            ((float*)Cout)[off] = v + bv;
          } else if (EPI == EPI_BF16_BIAS) {
            ((__bf16*)Cout)[off] = (__bf16)(v + bv);
          } else {
            float z = v + bv;
            ((__bf16*)Cout)[off] = (__bf16)(z / (1.f + __expf(-z)));
          }
        }
      }
    }
  }
}

// ---------------- attention pieces ----------------
// All take a batch index from blockIdx.z (z=0 == per-batch pointers, validated path).

__global__ __launch_bounds__(256) void q_softmax(__bf16* __restrict__ qkv) {
  qkv += (size_t)blockIdx.z * 4096 * 3072;
  int wg = blockIdx.x * 4 + (threadIdx.x >> 6);
  int l = threadIdx.x & 63;
  int row = wg >> 4, h = wg & 15;
  __bf16* p = qkv + (size_t)row * 3072 + h * 64 + l;
  float v = (float)*p * 0.125f;
  float m = v;
  #pragma unroll
  for (int s = 32; s; s >>= 1) m = fmaxf(m, __shfl_xor(m, s));
  float e = __expf(v - m);
  float sum = e;
  #pragma unroll
  for (int s = 32; s; s >>= 1) sum += __shfl_xor(sum, s);
  *p = (__bf16)(e / sum);
}

__global__ __launch_bounds__(256) void k_exp(__bf16* __restrict__ qkv, float* __restrict__ S) {
  qkv += (size_t)blockIdx.z * 4096 * 3072;
  S   += (size_t)blockIdx.z * 1024;
  int c = blockIdx.x * 256 + threadIdx.x;
  int n0 = blockIdx.y * 128;
  float sum = 0.f;
  __bf16* base = qkv + (size_t)n0 * 3072 + 1024 + c;
  for (int i = 0; i < 128; ++i) {
    __bf16* p = base + (size_t)i * 3072;
    float e = __expf((float)*p);
    __bf16 eb = (__bf16)e;
    *p = eb;
    sum += (float)eb;
  }
  atomicAdd(&S[c], sum);
}

__global__ __launch_bounds__(256) void ctx_gemm(const __bf16* __restrict__ qkv,
                                                float* __restrict__ ctx) {
  qkv += (size_t)blockIdx.z * 4096 * 3072;
  ctx += (size_t)blockIdx.z * 16 * 4096;
  int h = blockIdx.x;
  int k0base = blockIdx.y * 1024;
  __shared__ __bf16 sQ[64 * 32];
  __shared__ __bf16 sK[64 * 32];
  int tid = threadIdx.x, w = tid >> 6, l = tid & 63;
  int lr = l & 15, lk = (l >> 4) * 8;
  int srow = tid >> 3, scol = (tid & 7) * 8;
  f32x4 acc[4] = {};

  for (int kc = 0; kc < 1024; kc += 32) {
    size_t grow = (size_t)(k0base + kc + srow) * 3072;
    bf16x8 qv = *(const bf16x8*)(qkv + grow + h * 64 + scol);
    bf16x8 kv = *(const bf16x8*)(qkv + grow + 1024 + h * 64 + scol);
    __syncthreads();
    #pragma unroll
    for (int j = 0; j < 8; ++j) {
      sQ[(scol + j) * 32 + srow] = qv[j];
      sK[(scol + j) * 32 + srow] = kv[j];
    }
    __syncthreads();
    bf16x8 a = *(const bf16x8*)(sQ + (w * 16 + lr) * 32 + lk);
    #pragma unroll
    for (int n = 0; n < 4; ++n) {
      bf16x8 bb = *(const bf16x8*)(sK + (n * 16 + lr) * 32 + lk);
      acc[n] = __builtin_amdgcn_mfma_f32_16x16x32_bf16(a, bb, acc[n], 0, 0, 0);
    }
  }
  float* cbase = ctx + (size_t)h * 64 * 64;
  #pragma unroll
  for (int n = 0; n < 4; ++n) {
    int col = n * 16 + lr;
    #pragma unroll
    for (int j = 0; j < 4; ++j) {
      int row = w * 16 + (l >> 4) * 4 + j;
      atomicAdd(cbase + row * 64 + col, acc[n][j]);
    }
  }
}

__global__ __launch_bounds__(256) void pv_gemm(const __bf16* __restrict__ qkv,
                                               const float* __restrict__ ctx,
                                               const float* __restrict__ S,
                                               __bf16* __restrict__ outpv) {
  qkv   += (size_t)blockIdx.z * 4096 * 3072;
  ctx   += (size_t)blockIdx.z * 16 * 4096;
  S     += (size_t)blockIdx.z * 1024;
  outpv += (size_t)blockIdx.z * 4096 * 1024;
  int h = blockIdx.y;
  int row0 = blockIdx.x * 128;
  __shared__ __bf16 sC[64 * 64];
  int tid = threadIdx.x;
  const float* cb = ctx + (size_t)h * 4096;
  for (int i = tid; i < 4096; i += 256) {
    int d = i >> 6, e = i & 63;
    sC[e * 64 + d] = (__bf16)cb[i];
  }
  __syncthreads();
  int w = tid >> 6, l = tid & 63;
  int lr = l & 15, lk = (l >> 4) * 8;
  f32x4 acc[2][4] = {};
  const __bf16* vbase = qkv + 2048 + h * 64;
  #pragma unroll
  for (int kk = 0; kk < 64; kk += 32) {
    #pragma unroll
    for (int m = 0; m < 2; ++m) {
      int r = row0 + w * 32 + m * 16 + lr;
      bf16x8 a = *(const bf16x8*)(vbase + (size_t)r * 3072 + kk + lk);
      #pragma unroll
      for (int n = 0; n < 4; ++n) {
        bf16x8 bb = *(const bf16x8*)(sC + (n * 16 + lr) * 64 + kk + lk);
        acc[m][n] = __builtin_amdgcn_mfma_f32_16x16x32_bf16(a, bb, acc[m][n], 0, 0, 0);
      }
    }
  }
  #pragma unroll
  for (int m = 0; m < 2; ++m) {
    int rb = row0 + w * 32 + m * 16 + (l >> 4) * 4;
    #pragma unroll
    for (int n = 0; n < 4; ++n) {
      int e = n * 16 + lr;
      float inv = 1.0f / S[h * 64 + e];
      #pragma unroll
      for (int j = 0; j < 4; ++j)
        outpv[(size_t)(rb + j) * 1024 + h * 64 + e] = (__bf16)(acc[m][n][j] * inv);
    }
  }
}

// ---------------- LayerNorm (row of 1024, bf16 in -> bf16 out) ----------------
__global__ __launch_bounds__(256) void layernorm_k(const __bf16* __restrict__ attn,
                                                   const float* __restrict__ g,
                                                   const float* __restrict__ beta,
                                                   __bf16* __restrict__ out) {
  int row = blockIdx.x;
  int t = threadIdx.x;
  bf16x4 v4 = *(const bf16x4*)(attn + (size_t)row * 1024 + t * 4);
  float v0 = (float)v4[0], v1 = (float)v4[1], v2 = (float)v4[2], v3 = (float)v4[3];
  float s = v0 + v1 + v2 + v3;
  float ss = v0 * v0 + v1 * v1 + v2 * v2 + v3 * v3;
  #pragma unroll
  for (int sh = 32; sh; sh >>= 1) { s += __shfl_xor(s, sh); ss += __shfl_xor(ss, sh); }
  __shared__ float red[8];
  int w = t >> 6, l = t & 63;
  if (l == 0) { red[w] = s; red[4 + w] = ss; }
  __syncthreads();
  s = red[0] + red[1] + red[2] + red[3];
  ss = red[4] + red[5] + red[6] + red[7];
  float mu = s * (1.f / 1024.f);
  float var = ss * (1.f / 1024.f) - mu * mu;
  float rstd = rsqrtf(var + 1e-5f);
  float4 gg = *(const float4*)(g + t * 4);
  float4 bb = *(const float4*)(beta + t * 4);
  bf16x4 o;
  o[0] = (__bf16)((v0 - mu) * rstd * gg.x + bb.x);
  o[1] = (__bf16)((v1 - mu) * rstd * gg.y + bb.y);
  o[2] = (__bf16)((v2 - mu) * rstd * gg.z + bb.z);
  o[3] = (__bf16)((v3 - mu) * rstd * gg.w + bb.w);
  *(bf16x4*)(out + (size_t)row * 1024 + t * 4) = o;
}

// ---------------- launch ----------------

extern "C" void kernel_launch(void* const* d_in, const int* in_sizes, int n_in,
                              void* d_out, int out_size, void* d_ws, size_t ws_size,
                              hipStream_t stream) {
  const float* x     = (const float*)d_in[0];
  const float* W_qkv = (const float*)d_in[1];
  const float* W_out = (const float*)d_in[2];
  const float* b_out = (const float*)d_in[3];
  const float* ln_g  = (const float*)d_in[4];
  const float* ln_b  = (const float*)d_in[5];
  const float* W1    = (const float*)d_in[6];
  const float* b1    = (const float*)d_in[7];
  const float* W2    = (const float*)d_in[8];
  const float* b2    = (const float*)d_in[9];

  char* ws = (char*)d_ws;
  size_t off = 0;
  auto alloc = [&](size_t bytes) { void* p = ws + off; off += (bytes + 255) & ~(size_t)255; return p; };

  __bf16* wqkvT = (__bf16*)alloc(3072ull * 1024 * 2);
  __bf16* woutT = (__bf16*)alloc(1024ull * 1024 * 2);
  __bf16* w1T   = (__bf16*)alloc(4096ull * 1024 * 2);
  __bf16* w2T   = (__bf16*)alloc(1024ull * 4096 * 2);

  cvt_wT<<<dim3(32, 96), dim3(32, 8), 0, stream>>>(W_qkv, wqkvT, 1024, 3072);
  cvt_wT<<<dim3(32, 32), dim3(32, 8), 0, stream>>>(W_out, woutT, 1024, 1024);
  cvt_wT<<<dim3(32, 128), dim3(32, 8), 0, stream>>>(W1, w1T, 1024, 4096);
  cvt_wT<<<dim3(128, 32), dim3(32, 8), 0, stream>>>(W2, w2T, 4096, 1024);

  const size_t FULL_NEED = 196ull << 20;

  if (ws_size >= FULL_NEED) {
    // ---------- FULL path ----------
    float*  Sctx  = (float*)alloc((4096ull + 4 * 16 * 4096) * 4);
    __bf16* xb    = (__bf16*)alloc(16384ull * 1024 * 2);
    __bf16* qkv   = (__bf16*)alloc(16384ull * 3072 * 2);
    __bf16* outpv = (__bf16*)alloc(16384ull * 1024 * 2);

    float* S   = Sctx;
    float* ctx = Sctx + 4096;
    __bf16* attn = (__bf16*)((char*)qkv + (64ull << 20));
    __bf16* hln  = xb;
    __bf16* ffn1 = qkv;

    cvt_f32_bf16<<<16384, 256, 0, stream>>>(x, xb, 16777216L);
    zero_f32<<<260, 256, 0, stream>>>(Sctx, 266240);

    // QKV with fused q-softmax / k-exp+colsum epilogue
    gemm256<EPI_QKV><<<dim3(64, 12), 512, 0, stream>>>(xb, wqkvT, qkv, nullptr, 16384, 3072, 1024, S);
    ctx_gemm<<<dim3(16, 4, 4), 256, 0, stream>>>(qkv, ctx);
    pv_gemm<<<dim3(32, 16, 4), 256, 0, stream>>>(qkv, ctx, S, outpv);

    gemm256<EPI_BF16_BIAS><<<dim3(64, 4), 512, 0, stream>>>(outpv, woutT, attn, b_out, 16384, 1024, 1024, nullptr);
    layernorm_k<<<16384, 256, 0, stream>>>(attn, ln_g, ln_b, hln);
    gemm256<EPI_BF16_SILU><<<dim3(64, 16), 512, 0, stream>>>(hln, w1T, ffn1, b1, 16384, 4096, 1024, nullptr);
    gemm256<EPI_F32_BIAS><<<dim3(64, 4), 512, 0, stream>>>(ffn1, w2T, (float*)d_out, b2, 16384, 1024, 4096, nullptr);
  } else {
    // ---------- CHUNKED fallback (~112 MiB, separate-kernel attention) ----------
    float*  Sctx  = (float*)alloc(66560ull * 4);
    __bf16* xb    = (__bf16*)alloc(16384ull * 1024 * 2);
    __bf16* outpv = (__bf16*)alloc(16384ull * 1024 * 2);
    __bf16* qkv_b = (__bf16*)alloc(4096ull * 3072 * 2);

    float* S   = Sctx;
    float* ctx = Sctx + 1024;
    __bf16* attn = xb;
    __bf16* hln  = outpv;
    __bf16* fchunk = xb;

    cvt_f32_bf16<<<16384, 256, 0, stream>>>(x, xb, 16777216L);

    for (int b = 0; b < 4; ++b) {
      const __bf16* xb_b = xb + (size_t)b * 4096 * 1024;
      gemm256<EPI_BF16><<<dim3(16, 12), 512, 0, stream>>>(xb_b, wqkvT, qkv_b, nullptr, 4096, 3072, 1024, nullptr);
      zero_f32<<<65, 256, 0, stream>>>(Sctx, 66560);
      q_softmax<<<dim3(16384, 1, 1), 256, 0, stream>>>(qkv_b);
      k_exp<<<dim3(4, 32, 1), 256, 0, stream>>>(qkv_b, S);
      ctx_gemm<<<dim3(16, 4, 1), 256, 0, stream>>>(qkv_b, ctx);
      pv_gemm<<<dim3(32, 16, 1), 256, 0, stream>>>(qkv_b, ctx, S, outpv + (size_t)b * 4096 * 1024);
    }

    gemm256<EPI_BF16_BIAS><<<dim3(64, 4), 512, 0, stream>>>(outpv, woutT, attn, b_out, 16384, 1024, 1024, nullptr);
    layernorm_k<<<16384, 256, 0, stream>>>(attn, ln_g, ln_b, hln);

    for (int c = 0; c < 4; ++c) {
      const __bf16* h_c = hln + (size_t)c * 4096 * 1024;
      float* out_c = (float*)d_out + (size_t)c * 4096 * 1024;
      gemm256<EPI_BF16_SILU><<<dim3(16, 16), 512, 0, stream>>>(h_c, w1T, fchunk, b1, 4096, 4096, 1024, nullptr);
      gemm256<EPI_F32_BIAS><<<dim3(16, 4), 512, 0, stream>>>(fchunk, w2T, out_c, b2, 4096, 1024, 4096, nullptr);
    }
  }
}

// Round 13
// 527.211 us; speedup vs baseline: 1.1882x; 1.0324x over previous
//
#include <hip/hip_runtime.h>
#include <hip/hip_bf16.h>

typedef __bf16 bf16x8 __attribute__((ext_vector_type(8)));
typedef __bf16 bf16x4 __attribute__((ext_vector_type(4)));
typedef float  f32x4  __attribute__((ext_vector_type(4)));

#define GLOAD_LDS16(gp, lp) \
  __builtin_amdgcn_global_load_lds((const __attribute__((address_space(1))) void*)(gp), \
                                   (__attribute__((address_space(3))) void*)(lp), 16, 0, 0)
#define LGKM0 do { asm volatile("s_waitcnt lgkmcnt(0)" ::: "memory"); \
                   __builtin_amdgcn_sched_barrier(0); } while (0)

// ---------------- utility kernels ----------------

__global__ __launch_bounds__(256) void zero_f32(float* __restrict__ p, int n) {
  int i = (blockIdx.x * 256 + threadIdx.x) * 4;
  if (i < n) *(float4*)(p + i) = make_float4(0.f, 0.f, 0.f, 0.f);
}

__global__ __launch_bounds__(256) void cvt_f32_bf16(const float* __restrict__ in,
                                                    __bf16* __restrict__ out, long n) {
  long i = ((long)blockIdx.x * 256 + threadIdx.x) * 4;
  if (i >= n) return;
  float4 v = *(const float4*)(in + i);
  bf16x4 o;
  o[0] = (__bf16)v.x; o[1] = (__bf16)v.y; o[2] = (__bf16)v.z; o[3] = (__bf16)v.w;
  *(bf16x4*)(out + i) = o;
}

// W [K][N] f32 row-major  ->  WT [N][K] bf16 row-major
__global__ __launch_bounds__(256) void cvt_wT(const float* __restrict__ W,
                                              __bf16* __restrict__ WT, int K, int N) {
  __shared__ float t[32][33];
  int k0 = blockIdx.x * 32, n0 = blockIdx.y * 32;
  int tx = threadIdx.x, ty = threadIdx.y;   // block (32,8)
  #pragma unroll
  for (int i = 0; i < 32; i += 8)
    t[ty + i][tx] = W[(size_t)(k0 + ty + i) * N + n0 + tx];
  __syncthreads();
  #pragma unroll
  for (int i = 0; i < 32; i += 8)
    WT[(size_t)(n0 + ty + i) * K + k0 + tx] = (__bf16)t[tx][ty + i];
}

// Fused prologue: one launch covering x->bf16 cvt, Sctx zero, and all 4 weight
// transposes (regions by blockIdx.x; per-region bodies identical to the old kernels).
__global__ __launch_bounds__(256) void prep_all(
    const float* __restrict__ x, __bf16* __restrict__ xb,
    float* __restrict__ Sctx, int nS,
    const float* __restrict__ Wq, __bf16* __restrict__ WqT,
    const float* __restrict__ Wo, __bf16* __restrict__ WoT,
    const float* __restrict__ W1p, __bf16* __restrict__ W1T,
    const float* __restrict__ W2p, __bf16* __restrict__ W2T) {
  const int bid = blockIdx.x, tid = threadIdx.x;
  if (bid < 16384) {                       // x -> bf16 (16.7M elems, 4/thread)
    long i = ((long)bid * 256 + tid) * 4;
    float4 v = *(const float4*)(x + i);
    bf16x4 o;
    o[0] = (__bf16)v.x; o[1] = (__bf16)v.y; o[2] = (__bf16)v.z; o[3] = (__bf16)v.w;
    *(bf16x4*)(xb + i) = o;
    return;
  }
  if (bid < 16644) {                       // zero Sctx (bounds-checked)
    int i = ((bid - 16384) * 256 + tid) * 4;
    if (i < nS) *(float4*)(Sctx + i) = make_float4(0.f, 0.f, 0.f, 0.f);
    return;
  }
  const float* W; __bf16* WT; int K, N, local, kb, nb;
  if (bid < 19716)      { W = Wq;  WT = WqT; K = 1024; N = 3072; local = bid - 16644; kb = local & 31;  nb = local >> 5; }
  else if (bid < 20740) { W = Wo;  WT = WoT; K = 1024; N = 1024; local = bid - 19716; kb = local & 31;  nb = local >> 5; }
  else if (bid < 24836) { W = W1p; WT = W1T; K = 1024; N = 4096; local = bid - 20740; kb = local & 31;  nb = local >> 5; }
  else                  { W = W2p; WT = W2T; K = 4096; N = 1024; local = bid - 24836; kb = local & 127; nb = local >> 7; }
  __shared__ float t[32][33];
  int k0 = kb * 32, n0 = nb * 32;
  int tx = tid & 31, ty = tid >> 5;        // same mapping as dim3(32,8)
  #pragma unroll
  for (int i = 0; i < 32; i += 8)
    t[ty + i][tx] = W[(size_t)(k0 + ty + i) * N + n0 + tx];
  __syncthreads();
  #pragma unroll
  for (int i = 0; i < 32; i += 8)
    WT[(size_t)(n0 + ty + i) * K + k0 + tx] = (__bf16)t[tx][ty + i];
}

// ---- 256x256 GEMM, BK=64, 4 MFMA-phases/K-tile (race-screened r8 loop) ----
// 512 threads (8 waves 2Mx4N), dbuf LDS 128 KiB. vmcnt(8) at p1/p3 only.
// Swizzle: linear LDS dest; source octet o^((row>>1)&3); same involution on read.
// EPI_QKV: fused q-softmax (head dim lives in one wave: 4 regs x 16 lanes) and
// k-exp + column sums (atomicAdd once per col per block) in the epilogue.

enum { EPI_BF16 = 0, EPI_F32_BIAS = 1, EPI_BF16_SILU = 2, EPI_BF16_BIAS = 3, EPI_QKV = 4 };

template <int EPI>
__global__ __launch_bounds__(512, 1)
void gemm256(const __bf16* __restrict__ A, const __bf16* __restrict__ B,
             void* __restrict__ Cout, const float* __restrict__ bias,
             int M, int N, int K, float* __restrict__ Sq) {
  __shared__ __bf16 lds[65536];   // 128 KiB
  const int tid = threadIdx.x;
  const int w = tid >> 6, l = tid & 63;
  const int brow = blockIdx.x * 256;
  const int bcol = blockIdx.y * 256;
  const int wr = w >> 2, wc = w & 3;            // wave grid 2x4
  const int lr = l & 15;
  const int rdo8 = ((l >> 4) ^ ((lr >> 1) & 3)) << 3;   // swizzled read octet
  const int NT = K >> 6;                         // BK = 64

  const int aoff = (wr * 128 + lr) * 32 + rdo8;
  const int boff = 16384 + (wc * 64 + lr) * 32 + rdo8;

  const int srow = w * 16 + (l >> 2);
  const int soct8 = ((l & 3) ^ ((l >> 3) & 3)) * 8;
  const __bf16* pA0 = A + (size_t)(brow + srow) * K + soct8;
  const __bf16* pA1 = A + (size_t)(brow + 128 + srow) * K + soct8;
  const __bf16* pB0 = B + (size_t)(bcol + srow) * K + soct8;
  const __bf16* pB1 = B + (size_t)(bcol + 128 + srow) * K + soct8;

  auto stageA = [&](int k, int Tt) {
    size_t cofs = (size_t)Tt * 64 + k * 32;
    __bf16* d = lds + (Tt & 1) * 32768 + k * 8192 + w * 512;
    GLOAD_LDS16(pA0 + cofs, d);
    GLOAD_LDS16(pA1 + cofs, d + 4096);
  };
  auto stageB = [&](int k, int Tt) {
    size_t cofs = (size_t)Tt * 64 + k * 32;
    __bf16* d = lds + (Tt & 1) * 32768 + 16384 + k * 8192 + w * 512;
    GLOAD_LDS16(pB0 + cofs, d);
    GLOAD_LDS16(pB1 + cofs, d + 4096);
  };

  f32x4 acc[8][4] = {};
  bf16x8 afr[4], bfr[4];

  stageA(0, 0); stageB(0, 0);
  stageA(1, 0); stageB(1, 0);
  stageA(0, 1); stageB(0, 1);

  for (int T = 0; T < NT; ++T) {
    const int buf = (T & 1) * 32768;
    const bool s1 = (T + 1 < NT), s2 = (T + 2 < NT);

    // ---- p1: (mh0, kk0) ----
    if (s1) asm volatile("s_waitcnt vmcnt(8)" ::: "memory");
    else    asm volatile("s_waitcnt vmcnt(4)" ::: "memory");
    __builtin_amdgcn_s_barrier();
    {
      const __bf16* pb = lds + buf + boff;
      const __bf16* pa = lds + buf + aoff;
      #pragma unroll
      for (int n = 0; n < 4; ++n) bfr[n] = *(const bf16x8*)(pb + n * 512);
      #pragma unroll
      for (int m = 0; m < 4; ++m) afr[m] = *(const bf16x8*)(pa + m * 512);
      if (s1) stageA(1, T + 1);
      LGKM0;
      __builtin_amdgcn_s_setprio(1);
      #pragma unroll
      for (int m = 0; m < 4; ++m)
        #pragma unroll
        for (int n = 0; n < 4; ++n)
          acc[m][n] = __builtin_amdgcn_mfma_f32_16x16x32_bf16(afr[m], bfr[n], acc[m][n], 0, 0, 0);
      __builtin_amdgcn_s_setprio(0);
    }

    // ---- p2: (mh1, kk0), reuse bfr ----
    __builtin_amdgcn_s_barrier();
    {
      const __bf16* pa = lds + buf + aoff + 2048;
      #pragma unroll
      for (int m = 0; m < 4; ++m) afr[m] = *(const bf16x8*)(pa + m * 512);
      if (s1) stageB(1, T + 1);
      LGKM0;
      __builtin_amdgcn_s_setprio(1);
      #pragma unroll
      for (int m = 0; m < 4; ++m)
        #pragma unroll
        for (int n = 0; n < 4; ++n)
          acc[m + 4][n] = __builtin_amdgcn_mfma_f32_16x16x32_bf16(afr[m], bfr[n], acc[m + 4][n], 0, 0, 0);
      __builtin_amdgcn_s_setprio(0);
    }

    // ---- p3: (mh0, kk1) ----
    if (s1) asm volatile("s_waitcnt vmcnt(8)" ::: "memory");
    else    asm volatile("s_waitcnt vmcnt(0)" ::: "memory");
    __builtin_amdgcn_s_barrier();
    {
      const __bf16* pb = lds + buf + 8192 + boff;
      const __bf16* pa = lds + buf + 8192 + aoff;
      #pragma unroll
      for (int n = 0; n < 4; ++n) bfr[n] = *(const bf16x8*)(pb + n * 512);
      #pragma unroll
      for (int m = 0; m < 4; ++m) afr[m] = *(const bf16x8*)(pa + m * 512);
      if (s2) stageA(0, T + 2);
      LGKM0;
      __builtin_amdgcn_s_setprio(1);
      #pragma unroll
      for (int m = 0; m < 4; ++m)
        #pragma unroll
        for (int n = 0; n < 4; ++n)
          acc[m][n] = __builtin_amdgcn_mfma_f32_16x16x32_bf16(afr[m], bfr[n], acc[m][n], 0, 0, 0);
      __builtin_amdgcn_s_setprio(0);
    }

    // ---- p4: (mh1, kk1), reuse bfr ----
    __builtin_amdgcn_s_barrier();
    {
      const __bf16* pa = lds + buf + 8192 + aoff + 2048;
      #pragma unroll
      for (int m = 0; m < 4; ++m) afr[m] = *(const bf16x8*)(pa + m * 512);
      if (s2) stageB(0, T + 2);
      LGKM0;
      __builtin_amdgcn_s_setprio(1);
      #pragma unroll
      for (int m = 0; m < 4; ++m)
        #pragma unroll
        for (int n = 0; n < 4; ++n)
          acc[m + 4][n] = __builtin_amdgcn_mfma_f32_16x16x32_bf16(afr[m], bfr[n], acc[m + 4][n], 0, 0, 0);
      __builtin_amdgcn_s_setprio(0);
    }
  }

  // ---------------- epilogue ----------------
  if (EPI == EPI_QKV) {
    const int creg = bcol + wc * 64;     // wave col base (one 64-col head span)
    const int region = creg >> 10;       // 0=q, 1=k, 2=v
    if (region == 0) {
      // fused q-softmax over head dim (64 cols = 4 regs x 16 lanes)
      #pragma unroll
      for (int m = 0; m < 8; ++m) {
        int row0 = brow + wr * 128 + m * 16 + (l >> 4) * 4;
        #pragma unroll
        for (int j = 0; j < 4; ++j) {
          float v0 = acc[m][0][j] * 0.125f, v1 = acc[m][1][j] * 0.125f;
          float v2 = acc[m][2][j] * 0.125f, v3 = acc[m][3][j] * 0.125f;
          float mx = fmaxf(fmaxf(v0, v1), fmaxf(v2, v3));
          #pragma unroll
          for (int s = 1; s < 16; s <<= 1) mx = fmaxf(mx, __shfl_xor(mx, s));
          float e0 = __expf(v0 - mx), e1 = __expf(v1 - mx);
          float e2 = __expf(v2 - mx), e3 = __expf(v3 - mx);
          float sum = e0 + e1 + e2 + e3;
          #pragma unroll
          for (int s = 1; s < 16; s <<= 1) sum += __shfl_xor(sum, s);
          float inv = 1.f / sum;
          size_t ro = (size_t)(row0 + j) * N + creg + lr;
          ((__bf16*)Cout)[ro]      = (__bf16)(e0 * inv);
          ((__bf16*)Cout)[ro + 16] = (__bf16)(e1 * inv);
          ((__bf16*)Cout)[ro + 32] = (__bf16)(e2 * inv);
          ((__bf16*)Cout)[ro + 48] = (__bf16)(e3 * inv);
        }
      }
    } else if (region == 1) {
      // fused k-exp + column sums
      const int batch = brow >> 12;
      float csum[4] = {0.f, 0.f, 0.f, 0.f};
      #pragma unroll
      for (int m = 0; m < 8; ++m) {
        int row0 = brow + wr * 128 + m * 16 + (l >> 4) * 4;
        #pragma unroll
        for (int n = 0; n < 4; ++n) {
          int col = creg + n * 16 + lr;
          #pragma unroll
          for (int j = 0; j < 4; ++j) {
            float e = __expf(acc[m][n][j]);
            __bf16 eb = (__bf16)e;
            ((__bf16*)Cout)[(size_t)(row0 + j) * N + col] = eb;
            csum[n] += (float)eb;
          }
        }
      }
      #pragma unroll
      for (int n = 0; n < 4; ++n) {
        csum[n] += __shfl_xor(csum[n], 16);
        csum[n] += __shfl_xor(csum[n], 32);
      }
      if ((l >> 4) == 0) {
        #pragma unroll
        for (int n = 0; n < 4; ++n)
          atomicAdd(&Sq[batch * 1024 + (creg - 1024) + n * 16 + lr], csum[n]);
      }
    } else {
      // v region: plain bf16 store
      #pragma unroll
      for (int m = 0; m < 8; ++m) {
        int row0 = brow + wr * 128 + m * 16 + (l >> 4) * 4;
        #pragma unroll
        for (int n = 0; n < 4; ++n) {
          int col = creg + n * 16 + lr;
          #pragma unroll
          for (int j = 0; j < 4; ++j)
            ((__bf16*)Cout)[(size_t)(row0 + j) * N + col] = (__bf16)acc[m][n][j];
        }
      }
    }
  } else {
    #pragma unroll
    for (int m = 0; m < 8; ++m) {
      int row0 = brow + wr * 128 + m * 16 + (l >> 4) * 4;
      #pragma unroll
      for (int n = 0; n < 4; ++n) {
        int col = bcol + wc * 64 + n * 16 + lr;
        float bv = (EPI == EPI_BF16) ? 0.f : bias[col];
        #pragma unroll
        for (int j = 0; j < 4; ++j) {
          float v = acc[m][n][j];
          size_t off = (size_t)(row0 + j) * N + col;
          if (EPI == EPI_BF16) {
            ((__bf16*)Cout)[off] = (__bf16)v;
          } else if (EPI == EPI_F32_BIAS) {
            ((float*)Cout)[off] = v + bv;
          } else if (EPI == EPI_BF16_BIAS) {
            ((__bf16*)Cout)[off] = (__bf16)(v + bv);
          } else {
            float z = v + bv;
            ((__bf16*)Cout)[off] = (__bf16)(z / (1.f + __expf(-z)));
          }
        }
      }
    }
  }
}

// ---------------- attention pieces ----------------
// All take a batch index from blockIdx.z (z=0 == per-batch pointers, validated path).

__global__ __launch_bounds__(256) void q_softmax(__bf16* __restrict__ qkv) {
  qkv += (size_t)blockIdx.z * 4096 * 3072;
  int wg = blockIdx.x * 4 + (threadIdx.x >> 6);
  int l = threadIdx.x & 63;
  int row = wg >> 4, h = wg & 15;
  __bf16* p = qkv + (size_t)row * 3072 + h * 64 + l;
  float v = (float)*p * 0.125f;
  float m = v;
  #pragma unroll
  for (int s = 32; s; s >>= 1) m = fmaxf(m, __shfl_xor(m, s));
  float e = __expf(v - m);
  float sum = e;
  #pragma unroll
  for (int s = 32; s; s >>= 1) sum += __shfl_xor(sum, s);
  *p = (__bf16)(e / sum);
}

__global__ __launch_bounds__(256) void k_exp(__bf16* __restrict__ qkv, float* __restrict__ S) {
  qkv += (size_t)blockIdx.z * 4096 * 3072;
  S   += (size_t)blockIdx.z * 1024;
  int c = blockIdx.x * 256 + threadIdx.x;
  int n0 = blockIdx.y * 128;
  float sum = 0.f;
  __bf16* base = qkv + (size_t)n0 * 3072 + 1024 + c;
  for (int i = 0; i < 128; ++i) {
    __bf16* p = base + (size_t)i * 3072;
    float e = __expf((float)*p);
    __bf16 eb = (__bf16)e;
    *p = eb;
    sum += (float)eb;
  }
  atomicAdd(&S[c], sum);
}

__global__ __launch_bounds__(256) void ctx_gemm(const __bf16* __restrict__ qkv,
                                                float* __restrict__ ctx) {
  qkv += (size_t)blockIdx.z * 4096 * 3072;
  ctx += (size_t)blockIdx.z * 16 * 4096;
  int h = blockIdx.x;
  int k0base = blockIdx.y * 1024;
  __shared__ __bf16 sQ[64 * 32];
  __shared__ __bf16 sK[64 * 32];
  int tid = threadIdx.x, w = tid >> 6, l = tid & 63;
  int lr = l & 15, lk = (l >> 4) * 8;
  int srow = tid >> 3, scol = (tid & 7) * 8;
  f32x4 acc[4] = {};

  for (int kc = 0; kc < 1024; kc += 32) {
    size_t grow = (size_t)(k0base + kc + srow) * 3072;
    bf16x8 qv = *(const bf16x8*)(qkv + grow + h * 64 + scol);
    bf16x8 kv = *(const bf16x8*)(qkv + grow + 1024 + h * 64 + scol);
    __syncthreads();
    #pragma unroll
    for (int j = 0; j < 8; ++j) {
      sQ[(scol + j) * 32 + srow] = qv[j];
      sK[(scol + j) * 32 + srow] = kv[j];
    }
    __syncthreads();
    bf16x8 a = *(const bf16x8*)(sQ + (w * 16 + lr) * 32 + lk);
    #pragma unroll
    for (int n = 0; n < 4; ++n) {
      bf16x8 bb = *(const bf16x8*)(sK + (n * 16 + lr) * 32 + lk);
      acc[n] = __builtin_amdgcn_mfma_f32_16x16x32_bf16(a, bb, acc[n], 0, 0, 0);
    }
  }
  float* cbase = ctx + (size_t)h * 64 * 64;
  #pragma unroll
  for (int n = 0; n < 4; ++n) {
    int col = n * 16 + lr;
    #pragma unroll
    for (int j = 0; j < 4; ++j) {
      int row = w * 16 + (l >> 4) * 4 + j;
      atomicAdd(cbase + row * 64 + col, acc[n][j]);
    }
  }
}

__global__ __launch_bounds__(256) void pv_gemm(const __bf16* __restrict__ qkv,
                                               const float* __restrict__ ctx,
                                               const float* __restrict__ S,
                                               __bf16* __restrict__ outpv) {
  qkv   += (size_t)blockIdx.z * 4096 * 3072;
  ctx   += (size_t)blockIdx.z * 16 * 4096;
  S     += (size_t)blockIdx.z * 1024;
  outpv += (size_t)blockIdx.z * 4096 * 1024;
  int h = blockIdx.y;
  int row0 = blockIdx.x * 128;
  __shared__ __bf16 sC[64 * 64];
  int tid = threadIdx.x;
  const float* cb = ctx + (size_t)h * 4096;
  for (int i = tid; i < 4096; i += 256) {
    int d = i >> 6, e = i & 63;
    sC[e * 64 + d] = (__bf16)cb[i];
  }
  __syncthreads();
  int w = tid >> 6, l = tid & 63;
  int lr = l & 15, lk = (l >> 4) * 8;
  f32x4 acc[2][4] = {};
  const __bf16* vbase = qkv + 2048 + h * 64;
  #pragma unroll
  for (int kk = 0; kk < 64; kk += 32) {
    #pragma unroll
    for (int m = 0; m < 2; ++m) {
      int r = row0 + w * 32 + m * 16 + lr;
      bf16x8 a = *(const bf16x8*)(vbase + (size_t)r * 3072 + kk + lk);
      #pragma unroll
      for (int n = 0; n < 4; ++n) {
        bf16x8 bb = *(const bf16x8*)(sC + (n * 16 + lr) * 64 + kk + lk);
        acc[m][n] = __builtin_amdgcn_mfma_f32_16x16x32_bf16(a, bb, acc[m][n], 0, 0, 0);
      }
    }
  }
  #pragma unroll
  for (int m = 0; m < 2; ++m) {
    int rb = row0 + w * 32 + m * 16 + (l >> 4) * 4;
    #pragma unroll
    for (int n = 0; n < 4; ++n) {
      int e = n * 16 + lr;
      float inv = 1.0f / S[h * 64 + e];
      #pragma unroll
      for (int j = 0; j < 4; ++j)
        outpv[(size_t)(rb + j) * 1024 + h * 64 + e] = (__bf16)(acc[m][n][j] * inv);
    }
  }
}

// ---------------- LayerNorm (row of 1024, bf16 in -> bf16 out) ----------------
__global__ __launch_bounds__(256) void layernorm_k(const __bf16* __restrict__ attn,
                                                   const float* __restrict__ g,
                                                   const float* __restrict__ beta,
                                                   __bf16* __restrict__ out) {
  int row = blockIdx.x;
  int t = threadIdx.x;
  bf16x4 v4 = *(const bf16x4*)(attn + (size_t)row * 1024 + t * 4);
  float v0 = (float)v4[0], v1 = (float)v4[1], v2 = (float)v4[2], v3 = (float)v4[3];
  float s = v0 + v1 + v2 + v3;
  float ss = v0 * v0 + v1 * v1 + v2 * v2 + v3 * v3;
  #pragma unroll
  for (int sh = 32; sh; sh >>= 1) { s += __shfl_xor(s, sh); ss += __shfl_xor(ss, sh); }
  __shared__ float red[8];
  int w = t >> 6, l = t & 63;
  if (l == 0) { red[w] = s; red[4 + w] = ss; }
  __syncthreads();
  s = red[0] + red[1] + red[2] + red[3];
  ss = red[4] + red[5] + red[6] + red[7];
  float mu = s * (1.f / 1024.f);
  float var = ss * (1.f / 1024.f) - mu * mu;
  float rstd = rsqrtf(var + 1e-5f);
  float4 gg = *(const float4*)(g + t * 4);
  float4 bb = *(const float4*)(beta + t * 4);
  bf16x4 o;
  o[0] = (__bf16)((v0 - mu) * rstd * gg.x + bb.x);
  o[1] = (__bf16)((v1 - mu) * rstd * gg.y + bb.y);
  o[2] = (__bf16)((v2 - mu) * rstd * gg.z + bb.z);
  o[3] = (__bf16)((v3 - mu) * rstd * gg.w + bb.w);
  *(bf16x4*)(out + (size_t)row * 1024 + t * 4) = o;
}

// ---------------- launch ----------------

extern "C" void kernel_launch(void* const* d_in, const int* in_sizes, int n_in,
                              void* d_out, int out_size, void* d_ws, size_t ws_size,
                              hipStream_t stream) {
  const float* x     = (const float*)d_in[0];
  const float* W_qkv = (const float*)d_in[1];
  const float* W_out = (const float*)d_in[2];
  const float* b_out = (const float*)d_in[3];
  const float* ln_g  = (const float*)d_in[4];
  const float* ln_b  = (const float*)d_in[5];
  const float* W1    = (const float*)d_in[6];
  const float* b1    = (const float*)d_in[7];
  const float* W2    = (const float*)d_in[8];
  const float* b2    = (const float*)d_in[9];

  char* ws = (char*)d_ws;
  size_t off = 0;
  auto alloc = [&](size_t bytes) { void* p = ws + off; off += (bytes + 255) & ~(size_t)255; return p; };

  __bf16* wqkvT = (__bf16*)alloc(3072ull * 1024 * 2);
  __bf16* woutT = (__bf16*)alloc(1024ull * 1024 * 2);
  __bf16* w1T   = (__bf16*)alloc(4096ull * 1024 * 2);
  __bf16* w2T   = (__bf16*)alloc(1024ull * 4096 * 2);

  const size_t FULL_NEED = 196ull << 20;

  if (ws_size >= FULL_NEED) {
    // ---------- FULL path ----------
    float*  Sctx  = (float*)alloc((4096ull + 4 * 16 * 4096) * 4);
    __bf16* xb    = (__bf16*)alloc(16384ull * 1024 * 2);
    __bf16* qkv   = (__bf16*)alloc(16384ull * 3072 * 2);
    __bf16* outpv = (__bf16*)alloc(16384ull * 1024 * 2);

    float* S   = Sctx;
    float* ctx = Sctx + 4096;
    __bf16* attn = (__bf16*)((char*)qkv + (64ull << 20));
    __bf16* hln  = xb;
    __bf16* ffn1 = qkv;

    // fused prologue: x->bf16, Sctx zero, 4 weight transposes, one launch
    prep_all<<<28932, 256, 0, stream>>>(x, xb, Sctx, 266240,
                                        W_qkv, wqkvT, W_out, woutT, W1, w1T, W2, w2T);

    // QKV with fused q-softmax / k-exp+colsum epilogue
    gemm256<EPI_QKV><<<dim3(64, 12), 512, 0, stream>>>(xb, wqkvT, qkv, nullptr, 16384, 3072, 1024, S);
    ctx_gemm<<<dim3(16, 4, 4), 256, 0, stream>>>(qkv, ctx);
    pv_gemm<<<dim3(32, 16, 4), 256, 0, stream>>>(qkv, ctx, S, outpv);

    gemm256<EPI_BF16_BIAS><<<dim3(64, 4), 512, 0, stream>>>(outpv, woutT, attn, b_out, 16384, 1024, 1024, nullptr);
    layernorm_k<<<16384, 256, 0, stream>>>(attn, ln_g, ln_b, hln);
    gemm256<EPI_BF16_SILU><<<dim3(64, 16), 512, 0, stream>>>(hln, w1T, ffn1, b1, 16384, 4096, 1024, nullptr);
    gemm256<EPI_F32_BIAS><<<dim3(64, 4), 512, 0, stream>>>(ffn1, w2T, (float*)d_out, b2, 16384, 1024, 4096, nullptr);
  } else {
    // ---------- CHUNKED fallback (~112 MiB, separate-kernel attention) ----------
    float*  Sctx  = (float*)alloc(66560ull * 4);
    __bf16* xb    = (__bf16*)alloc(16384ull * 1024 * 2);
    __bf16* outpv = (__bf16*)alloc(16384ull * 1024 * 2);
    __bf16* qkv_b = (__bf16*)alloc(4096ull * 3072 * 2);

    float* S   = Sctx;
    float* ctx = Sctx + 1024;
    __bf16* attn = xb;
    __bf16* hln  = outpv;
    __bf16* fchunk = xb;

    prep_all<<<28932, 256, 0, stream>>>(x, xb, Sctx, 66560,
                                        W_qkv, wqkvT, W_out, woutT, W1, w1T, W2, w2T);

    for (int b = 0; b < 4; ++b) {
      const __bf16* xb_b = xb + (size_t)b * 4096 * 1024;
      gemm256<EPI_BF16><<<dim3(16, 12), 512, 0, stream>>>(xb_b, wqkvT, qkv_b, nullptr, 4096, 3072, 1024, nullptr);
      zero_f32<<<65, 256, 0, stream>>>(Sctx, 66560);
      q_softmax<<<dim3(16384, 1, 1), 256, 0, stream>>>(qkv_b);
      k_exp<<<dim3(4, 32, 1), 256, 0, stream>>>(qkv_b, S);
      ctx_gemm<<<dim3(16, 4, 1), 256, 0, stream>>>(qkv_b, ctx);
      pv_gemm<<<dim3(32, 16, 1), 256, 0, stream>>>(qkv_b, ctx, S, outpv + (size_t)b * 4096 * 1024);
    }

    gemm256<EPI_BF16_BIAS><<<dim3(64, 4), 512, 0, stream>>>(outpv, woutT, attn, b_out, 16384, 1024, 1024, nullptr);
    layernorm_k<<<16384, 256, 0, stream>>>(attn, ln_g, ln_b, hln);

    for (int c = 0; c < 4; ++c) {
      const __bf16* h_c = hln + (size_t)c * 4096 * 1024;
      float* out_c = (float*)d_out + (size_t)c * 4096 * 1024;
      gemm256<EPI_BF16_SILU><<<dim3(16, 16), 512, 0, stream>>>(h_c, w1T, fchunk, b1, 4096, 4096, 1024, nullptr);
      gemm256<EPI_F32_BIAS><<<dim3(16, 4), 512, 0, stream>>>(fchunk, w2T, out_c, b2, 4096, 1024, 4096, nullptr);
    }
  }
}